// Round 3
// baseline (147.760 us; speedup 1.0000x reference)
//
#include <hip/hip_runtime.h>
#include <cstdint>
#include <cstddef>

#define D_MODEL 512
#define SEQ_T 2048
#define NHEADS 8
#define HDIM 64

typedef __attribute__((ext_vector_type(8))) short bf16x8;
typedef __attribute__((ext_vector_type(4))) float f32x4;
typedef __attribute__((ext_vector_type(16))) float f32x16;

__device__ __forceinline__ unsigned short f2bf(float f) {
  unsigned int u = __float_as_uint(f);
  u += 0x7FFFu + ((u >> 16) & 1u);
  return (unsigned short)(u >> 16);
}

// pack two f32 -> two bf16 in one uint (round via +0x8000, v_perm)
__device__ __forceinline__ unsigned int pack_bf16(float lo, float hi) {
  unsigned int a = __float_as_uint(lo) + 0x8000u;
  unsigned int b = __float_as_uint(hi) + 0x8000u;
  return __builtin_amdgcn_perm(b, a, 0x07060302u);
}

// Q pre-scaled by 1/sqrt(64) * log2(e) so softmax runs in exp2 domain.
#define QSCALE 0.18033688011112043f
// fixed softmax shift: p = exp2(s - SSHIFT); common factor cancels in O/l.
#define SSHIFT 16.0f

// async global->LDS, 16B per lane. LDS dest = wave-uniform base + lane*16.
__device__ __forceinline__ void async_lds16(const unsigned short* g,
                                            unsigned short* l) {
  __builtin_amdgcn_global_load_lds(
      (const __attribute__((address_space(1))) void*)g,
      (__attribute__((address_space(3))) void*)l, 16, 0, 0);
}

// ---------------------------------------------------------------------------
// Fused prep: [0,2048) cast x -> bf16; [2048,2240) transpose W_qkv;
// [2240,2304) transpose W_out.
// ---------------------------------------------------------------------------
__global__ __launch_bounds__(256) void prep_kernel(
    const float* __restrict__ x, const float* __restrict__ W_qkv,
    const float* __restrict__ W_out, unsigned short* __restrict__ xb,
    unsigned short* __restrict__ Wqkt, unsigned short* __restrict__ Wot) {
  __shared__ float tile[64][65];
  const int bid = blockIdx.x;
  if (bid < 2048) {
    int i = (bid * 256 + threadIdx.x) * 8;
    float4 a = *(const float4*)(x + i);
    float4 b = *(const float4*)(x + i + 4);
    ushort4 lo = {f2bf(a.x), f2bf(a.y), f2bf(a.z), f2bf(a.w)};
    ushort4 hi = {f2bf(b.x), f2bf(b.y), f2bf(b.z), f2bf(b.w)};
    *(ushort4*)(xb + i) = lo;
    *(ushort4*)(xb + i + 4) = hi;
    return;
  }
  const float* src;
  unsigned short* dst;
  int R = 512, C, c0, r0;
  if (bid < 2048 + 192) {
    int t = bid - 2048;
    C = 1536; c0 = (t % 24) * 64; r0 = (t / 24) * 64;
    src = W_qkv; dst = Wqkt;
  } else {
    int t = bid - 2240;
    C = 512; c0 = (t & 7) * 64; r0 = (t >> 3) * 64;
    src = W_out; dst = Wot;
  }
  for (int i = threadIdx.x; i < 64 * 64; i += 256) {
    int r = i >> 6, c = i & 63;
    tile[r][c] = src[(size_t)(r0 + r) * C + c0 + c];
  }
  __syncthreads();
  for (int i = threadIdx.x; i < 64 * 64; i += 256) {
    int c = i >> 6, r = i & 63;
    dst[(size_t)(c0 + c) * R + r0 + r] = f2bf(tile[r][c]);
  }
}

// ---------------------------------------------------------------------------
// Kernel 1: QKV projection, bf16 MFMA. 128x128 tile, BK=64 (8 K-iters),
// XOR-swizzled LDS (16B chunk ^= row&7) -> conflict-free b128 fragment reads.
// Epilogue: Q -> bf16 [bh][d][t] TRANSPOSED packed ushort4 (pre-scaled);
// V -> bf16 [bh][dv][t] packed ushort4; K -> bf16 [bh][t][d] scalar.
// ---------------------------------------------------------------------------
__global__ __launch_bounds__(256) void gemm_qkv_mfma(
    const unsigned short* __restrict__ xb, const unsigned short* __restrict__ Wt,
    const float* __restrict__ bias, unsigned short* __restrict__ Qtb,
    unsigned short* __restrict__ Kb, unsigned short* __restrict__ Vtb) {
  __shared__ unsigned short As[128 * 64];
  __shared__ unsigned short Bs[128 * 64];
  const int tid = threadIdx.x;
  const int w = tid >> 6, lane = tid & 63;
  const int quad = lane >> 4, l15 = lane & 15;
  const int wm = w >> 1, wn = w & 1;
  const int m0 = blockIdx.x * 128, n0 = blockIdx.y * 128;

  const int srow = tid >> 3;                   // 0..31
  const int schunk = (tid & 7) ^ (srow & 7);   // logical chunk loaded
  const unsigned short* ga = xb + (size_t)(m0 + srow) * 512 + schunk * 8;
  const unsigned short* gb = Wt + (size_t)(n0 + srow) * 512 + schunk * 8;
  unsigned short* lA = As + tid * 8;
  unsigned short* lB = Bs + tid * 8;

  f32x4 acc[4][4] = {};
  for (int k0 = 0; k0 < 512; k0 += 64) {
#pragma unroll
    for (int rr = 0; rr < 4; ++rr) {
      async_lds16(ga + (size_t)rr * 32 * 512 + k0, lA + rr * 2048);
      async_lds16(gb + (size_t)rr * 32 * 512 + k0, lB + rr * 2048);
    }
    __syncthreads();
    bf16x8 af[4][2], bfr[4][2];
#pragma unroll
    for (int mb = 0; mb < 4; ++mb) {
      int row = wm * 64 + mb * 16 + l15;
#pragma unroll
      for (int kk = 0; kk < 2; ++kk) {
        int slot = (kk * 4 + quad) ^ (row & 7);
        af[mb][kk] = *(const bf16x8*)&As[row * 64 + slot * 8];
      }
    }
#pragma unroll
    for (int nb = 0; nb < 4; ++nb) {
      int row = wn * 64 + nb * 16 + l15;
#pragma unroll
      for (int kk = 0; kk < 2; ++kk) {
        int slot = (kk * 4 + quad) ^ (row & 7);
        bfr[nb][kk] = *(const bf16x8*)&Bs[row * 64 + slot * 8];
      }
    }
#pragma unroll
    for (int mb = 0; mb < 4; ++mb)
#pragma unroll
      for (int nb = 0; nb < 4; ++nb) {
        acc[mb][nb] = __builtin_amdgcn_mfma_f32_16x16x32_bf16(
            af[mb][0], bfr[nb][0], acc[mb][nb], 0, 0, 0);
        acc[mb][nb] = __builtin_amdgcn_mfma_f32_16x16x32_bf16(
            af[mb][1], bfr[nb][1], acc[mb][nb], 0, 0, 0);
      }
    __syncthreads();
  }

  const int cbase = n0 + wn * 64;
  const int three = cbase >> 9;          // 0:Q 1:K 2:V
  const int h = (cbase >> 6) & 7;
  const int bh = ((m0 >> 11) << 3) + h;
  const int t0 = (m0 & 2047) + wm * 64;
  float bv[4];
#pragma unroll
  for (int nb = 0; nb < 4; ++nb) bv[nb] = bias[cbase + nb * 16 + l15];

  if (three == 0) {
    // Q transposed [bh][d][t], pre-scaled, packed along t
#pragma unroll
    for (int mb = 0; mb < 4; ++mb)
#pragma unroll
      for (int nb = 0; nb < 4; ++nb) {
        int trow = t0 + mb * 16 + quad * 4;
        ushort4 v = {f2bf((acc[mb][nb][0] + bv[nb]) * QSCALE),
                     f2bf((acc[mb][nb][1] + bv[nb]) * QSCALE),
                     f2bf((acc[mb][nb][2] + bv[nb]) * QSCALE),
                     f2bf((acc[mb][nb][3] + bv[nb]) * QSCALE)};
        *(ushort4*)(Qtb + ((size_t)bh * HDIM + nb * 16 + l15) * SEQ_T + trow) = v;
      }
  } else if (three == 2) {
    // V transposed [bh][dv][t], packed along t
#pragma unroll
    for (int mb = 0; mb < 4; ++mb)
#pragma unroll
      for (int nb = 0; nb < 4; ++nb) {
        int trow = t0 + mb * 16 + quad * 4;
        ushort4 v = {f2bf(acc[mb][nb][0] + bv[nb]), f2bf(acc[mb][nb][1] + bv[nb]),
                     f2bf(acc[mb][nb][2] + bv[nb]), f2bf(acc[mb][nb][3] + bv[nb])};
        *(ushort4*)(Vtb + ((size_t)bh * HDIM + nb * 16 + l15) * SEQ_T + trow) = v;
      }
  } else {
    // K row-major [bh][t][d] (required for attn A-fragment contiguity)
#pragma unroll
    for (int mb = 0; mb < 4; ++mb)
#pragma unroll
      for (int nb = 0; nb < 4; ++nb)
#pragma unroll
        for (int r = 0; r < 4; ++r) {
          int trow = t0 + mb * 16 + quad * 4 + r;
          Kb[((size_t)bh * SEQ_T + trow) * HDIM + nb * 16 + l15] =
              f2bf(acc[mb][nb][r] + bv[nb]);
        }
  }
}

// ---------------------------------------------------------------------------
// Kernel 2 (v6d): causal flash attention on 32x32x16 MFMAs.
//  - 128-query blocks (4 waves x 32 q), 512 blocks = 2/CU; CU-slot pairs
//    (15-k, k) give exactly 34 key-tiles per CU; longest-first dispatch
//  - per-query LDS read traffic halved vs 16x16 path (32x32 A-frags)
//  - P redistribution via per-wave swizzled LDS Pt round-trip (v5-proven
//    mechanism; permlane variant NaN'd -- bisect isolates it)
//  - l via VALU adds + one __shfl_xor (no ones-MFMA)
//  - double-buffered swizzled LDS staging, 1 barrier/tile
//  - fixed-shift softmax p = exp2(s-16)
// ---------------------------------------------------------------------------
__global__ __launch_bounds__(256, 2) void attn_mfma6(
    const unsigned short* __restrict__ Qtb, const unsigned short* __restrict__ Kb,
    const unsigned short* __restrict__ Vtb, unsigned short* __restrict__ AOb) {
  __shared__ __align__(16) unsigned short Ks[2][64 * 64];
  __shared__ __align__(16) unsigned short Vs[2][64 * 64];
  __shared__ __align__(16) unsigned short Pt[4][32 * 64];
  const int tid = threadIdx.x;
  const int w = tid >> 6, lane = tid & 63;
  const int l31 = lane & 31, h = lane >> 5;
  const int r7l = lane & 7;

  // balanced (bh, qt2) mapping: co-resident pair sums to 34 key-tiles
  const int bid = blockIdx.x;
  const int xcd = bid & 7;
  const int j = bid >> 3;            // 0..63
  const int c = j & 31, g = j >> 5;  // CU slot within XCD, co-res slot
  const int kslot = c >> 2;
  const int bh = xcd + 8 * (c & 3);
  const int qt2 = g ? kslot : (15 - kslot);
  const int nmain = 2 * qt2;         // full (unmasked) 64-key tiles

  const unsigned short* kbase = Kb + (size_t)bh * SEQ_T * HDIM;
  const unsigned short* vbase = Vtb + (size_t)bh * HDIM * SEQ_T;
  const int sr = tid >> 3;             // staging row 0..31
  const int lc = tid & 7;              // logical 16B chunk
  const int scol = lc * 8;
  const int swc = (lc ^ (sr & 7)) * 8; // swizzled slot offset

  // Q B-fragments: qf[c] = Q[d = c*16 + h*8 + j][q = qglob]
  const int qglob = qt2 * 128 + w * 32 + l31;
  bf16x8 qf[4];
  {
    unsigned short qraw[32];
    const unsigned short* qp =
        Qtb + ((size_t)bh * HDIM + h * 8) * SEQ_T + qglob;
#pragma unroll
    for (int cc = 0; cc < 4; ++cc)
#pragma unroll
      for (int jj = 0; jj < 8; ++jj)
        qraw[cc * 8 + jj] = qp[(size_t)(cc * 16 + jj) * SEQ_T];
#pragma unroll
    for (int cc = 0; cc < 4; ++cc) qf[cc] = *(const bf16x8*)(qraw + cc * 8);
  }

  f32x16 O0 = {0.f, 0.f, 0.f, 0.f, 0.f, 0.f, 0.f, 0.f,
               0.f, 0.f, 0.f, 0.f, 0.f, 0.f, 0.f, 0.f};
  f32x16 O1 = O0;
  float l_acc = 0.f;

  // tile compute: QK^T (8 MFMA) -> exp2/pack -> Pt round-trip -> PV (8 MFMA)
  auto tile_compute = [&](int cur, int lim, bool masked) {
    f32x16 S0 = {0.f, 0.f, 0.f, 0.f, 0.f, 0.f, 0.f, 0.f,
                 0.f, 0.f, 0.f, 0.f, 0.f, 0.f, 0.f, 0.f};
    f32x16 S1 = S0;
#pragma unroll
    for (int cc = 0; cc < 4; ++cc) {
      const int slot = ((cc << 1) | h) ^ r7l;
      const bf16x8 k0 = *(const bf16x8*)&Ks[cur][l31 * 64 + slot * 8];
      const bf16x8 k1 = *(const bf16x8*)&Ks[cur][(32 + l31) * 64 + slot * 8];
      S0 = __builtin_amdgcn_mfma_f32_32x32x16_bf16(k0, qf[cc], S0, 0, 0, 0);
      S1 = __builtin_amdgcn_mfma_f32_32x32x16_bf16(k1, qf[cc], S1, 0, 0, 0);
    }
    // lane holds S[key = kl][q = l31]; kl = (r&3)+8*(r>>2)+4h (S0), +32 (S1).
    // pk word m packs keys K,K+1 with K = 8*(m>>1)+2*(m&1)+4h.
#pragma unroll
    for (int m = 0; m < 8; ++m) {
      float p0 = __builtin_amdgcn_exp2f(S0[2 * m] - SSHIFT);
      float p1 = __builtin_amdgcn_exp2f(S0[2 * m + 1] - SSHIFT);
      float p2 = __builtin_amdgcn_exp2f(S1[2 * m] - SSHIFT);
      float p3 = __builtin_amdgcn_exp2f(S1[2 * m + 1] - SSHIFT);
      if (masked) {
        const int r0 = 2 * m, r1 = 2 * m + 1;
        const int kl0 = (r0 & 3) + 8 * (r0 >> 2) + 4 * h;
        const int kl1 = (r1 & 3) + 8 * (r1 >> 2) + 4 * h;
        p0 = (kl0 > lim) ? 0.f : p0;
        p1 = (kl1 > lim) ? 0.f : p1;
        p2 = (kl0 + 32 > lim) ? 0.f : p2;
        p3 = (kl1 + 32 > lim) ? 0.f : p3;
      }
      l_acc += (p0 + p1) + (p2 + p3);
      // Pt[w][q][key] logical, chunk c stored at slot c^(q&7); q = l31.
      // S0 word: key K = 8*(m>>1)+2*(m&1)+4h -> chunk m>>1, within 2(m&1)+4h.
      const int within = 2 * (m & 1) + 4 * h;
      const int slot0 = (m >> 1) ^ r7l;
      const int slot1 = ((m >> 1) + 4) ^ r7l;  // S1: keys +32 -> chunks 4..7
      *(unsigned int*)&Pt[w][l31 * 64 + slot0 * 8 + within] = pack_bf16(p0, p1);
      *(unsigned int*)&Pt[w][l31 * 64 + slot1 * 8 + within] = pack_bf16(p2, p3);
    }
    // PV: chunk t covers keys 16t..16t+15; B-frag needs keys 16t+8h+j
    // = logical chunk (2t+h) of row q -> same slot formula as Vs rows.
#pragma unroll
    for (int t = 0; t < 4; ++t) {
      const int slot = ((t << 1) | h) ^ r7l;
      const bf16x8 pb = *(const bf16x8*)&Pt[w][l31 * 64 + slot * 8];
      const bf16x8 v0 = *(const bf16x8*)&Vs[cur][l31 * 64 + slot * 8];
      const bf16x8 v1 = *(const bf16x8*)&Vs[cur][(32 + l31) * 64 + slot * 8];
      O0 = __builtin_amdgcn_mfma_f32_32x32x16_bf16(v0, pb, O0, 0, 0, 0);
      O1 = __builtin_amdgcn_mfma_f32_32x32x16_bf16(v1, pb, O1, 0, 0, 0);
    }
  };

  // stage tile 0 into buffer 0
  {
    const unsigned short* kp = kbase + (size_t)sr * 64 + scol;
    uint4 rk0 = *(const uint4*)kp;
    uint4 rk1 = *(const uint4*)(kp + 32 * 64);
    const unsigned short* vp = vbase + (size_t)sr * SEQ_T + scol;
    uint4 rv0 = *(const uint4*)vp;
    uint4 rv1 = *(const uint4*)(vp + 32 * SEQ_T);
    *(uint4*)&Ks[0][sr * 64 + swc] = rk0;
    *(uint4*)&Ks[0][(sr + 32) * 64 + swc] = rk1;
    *(uint4*)&Vs[0][sr * 64 + swc] = rv0;
    *(uint4*)&Vs[0][(sr + 32) * 64 + swc] = rv1;
  }
  __syncthreads();

  // ---- main loop: fully-unmasked tiles, branch-free ----
  for (int i = 0; i < nmain; ++i) {
    const int cur = i & 1;
    uint4 rk0, rk1, rv0, rv1;
    {
      const int nkt = i + 1;  // i+1 <= nmain: always a valid tile
      const unsigned short* kp = kbase + (size_t)(nkt * 64 + sr) * 64 + scol;
      rk0 = *(const uint4*)kp;
      rk1 = *(const uint4*)(kp + 32 * 64);
      const unsigned short* vp = vbase + (size_t)sr * SEQ_T + nkt * 64 + scol;
      rv0 = *(const uint4*)vp;
      rv1 = *(const uint4*)(vp + 32 * SEQ_T);
    }
    tile_compute(cur, 0, false);
    const int nxt = cur ^ 1;
    *(uint4*)&Ks[nxt][sr * 64 + swc] = rk0;
    *(uint4*)&Ks[nxt][(sr + 32) * 64 + swc] = rk1;
    *(uint4*)&Vs[nxt][sr * 64 + swc] = rv0;
    *(uint4*)&Vs[nxt][(sr + 32) * 64 + swc] = rv1;
    __syncthreads();
  }

  // ---- diagonal tile A (kt = nmain): keys 128*qt2 .. +63 ----
  {
    const int cur = nmain & 1;
    const int nkt = nmain + 1;
    const unsigned short* kp = kbase + (size_t)(nkt * 64 + sr) * 64 + scol;
    uint4 rk0 = *(const uint4*)kp;
    uint4 rk1 = *(const uint4*)(kp + 32 * 64);
    const unsigned short* vp = vbase + (size_t)sr * SEQ_T + nkt * 64 + scol;
    uint4 rv0 = *(const uint4*)vp;
    uint4 rv1 = *(const uint4*)(vp + 32 * SEQ_T);
    tile_compute(cur, w * 32 + l31, true);
    const int nxt = cur ^ 1;
    *(uint4*)&Ks[nxt][sr * 64 + swc] = rk0;
    *(uint4*)&Ks[nxt][(sr + 32) * 64 + swc] = rk1;
    *(uint4*)&Vs[nxt][sr * 64 + swc] = rv0;
    *(uint4*)&Vs[nxt][(sr + 32) * 64 + swc] = rv1;
    __syncthreads();
  }

  // ---- diagonal tile B (kt = nmain+1): keys +64..+127; waves 0,1 are
  // fully masked (all keys > all their queries) -> skip (wave-uniform) ----
  if (w >= 2) {
    const int cur = (nmain + 1) & 1;
    tile_compute(cur, w * 32 + l31 - 64, true);
  }

  // ---- reduce l across the two half-waves holding column q ----
  l_acc += __shfl_xor(l_acc, 32, 64);
  // safety clamp: any residual l=0 bug shows as finite error, not NaN
  const float inv = 1.0f / fmaxf(l_acc, 1e-30f);
  const int bb = bh >> 3, hh = bh & 7;
  unsigned short* dst = AOb + ((size_t)bb * SEQ_T + qglob) * D_MODEL + (hh << 6);
#pragma unroll
  for (int rg = 0; rg < 4; ++rg) {
    ushort4 o0 = {f2bf(O0[4 * rg + 0] * inv), f2bf(O0[4 * rg + 1] * inv),
                  f2bf(O0[4 * rg + 2] * inv), f2bf(O0[4 * rg + 3] * inv)};
    *(ushort4*)(dst + 8 * rg + 4 * h) = o0;
    ushort4 o1 = {f2bf(O1[4 * rg + 0] * inv), f2bf(O1[4 * rg + 1] * inv),
                  f2bf(O1[4 * rg + 2] * inv), f2bf(O1[4 * rg + 3] * inv)};
    *(ushort4*)(dst + 32 + 8 * rg + 4 * h) = o1;
  }
}

// ---------------------------------------------------------------------------
// Kernel 3: output projection, bf16 MFMA. 64x128 tile (512 blocks, 2/CU),
// BK=64 swizzled. AOb[8192][512] @ Wot[512][512]^T + b -> fp32 out.
// ---------------------------------------------------------------------------
__global__ __launch_bounds__(256) void gemm_out_mfma(
    const unsigned short* __restrict__ AOb, const unsigned short* __restrict__ Wot,
    const float* __restrict__ bias, float* __restrict__ out) {
  __shared__ unsigned short As[64 * 64];
  __shared__ unsigned short Bs[128 * 64];
  const int tid = threadIdx.x;
  const int w = tid >> 6, lane = tid & 63;
  const int quad = lane >> 4, l15 = lane & 15;
  const int m0 = blockIdx.x * 64, n0 = blockIdx.y * 128;

  const int srow = tid >> 3;
  const int schunk = (tid & 7) ^ (srow & 7);
  const unsigned short* ga = AOb + (size_t)(m0 + srow) * 512 + schunk * 8;
  const unsigned short* gb = Wot + (size_t)(n0 + srow) * 512 + schunk * 8;
  unsigned short* lA = As + tid * 8;
  unsigned short* lB = Bs + tid * 8;

  f32x4 acc[4][2] = {};
  for (int k0 = 0; k0 < 512; k0 += 64) {
#pragma unroll
    for (int rr = 0; rr < 2; ++rr)
      async_lds16(ga + (size_t)rr * 32 * 512 + k0, lA + rr * 2048);
#pragma unroll
    for (int rr = 0; rr < 4; ++rr)
      async_lds16(gb + (size_t)rr * 32 * 512 + k0, lB + rr * 2048);
    __syncthreads();
    bf16x8 af[4][2], bfr[2][2];
#pragma unroll
    for (int mb = 0; mb < 4; ++mb) {
      int row = mb * 16 + l15;
#pragma unroll
      for (int kk = 0; kk < 2; ++kk) {
        int slot = (kk * 4 + quad) ^ (row & 7);
        af[mb][kk] = *(const bf16x8*)&As[row * 64 + slot * 8];
      }
    }
#pragma unroll
    for (int nb = 0; nb < 2; ++nb) {
      int row = w * 32 + nb * 16 + l15;
#pragma unroll
      for (int kk = 0; kk < 2; ++kk) {
        int slot = (kk * 4 + quad) ^ (row & 7);
        bfr[nb][kk] = *(const bf16x8*)&Bs[row * 64 + slot * 8];
      }
    }
#pragma unroll
    for (int mb = 0; mb < 4; ++mb)
#pragma unroll
      for (int nb = 0; nb < 2; ++nb) {
        acc[mb][nb] = __builtin_amdgcn_mfma_f32_16x16x32_bf16(
            af[mb][0], bfr[nb][0], acc[mb][nb], 0, 0, 0);
        acc[mb][nb] = __builtin_amdgcn_mfma_f32_16x16x32_bf16(
            af[mb][1], bfr[nb][1], acc[mb][nb], 0, 0, 0);
      }
    __syncthreads();
  }

  const int cbase = n0 + w * 32;
  float bv[2];
#pragma unroll
  for (int nb = 0; nb < 2; ++nb) bv[nb] = bias[cbase + nb * 16 + l15];
#pragma unroll
  for (int mb = 0; mb < 4; ++mb)
#pragma unroll
    for (int nb = 0; nb < 2; ++nb)
#pragma unroll
      for (int r = 0; r < 4; ++r)
        out[(size_t)(m0 + mb * 16 + quad * 4 + r) * 512 + cbase + nb * 16 +
            l15] = acc[mb][nb][r] + bv[nb];
}

// ---------------------------------------------------------------------------
extern "C" void kernel_launch(void* const* d_in, const int* in_sizes, int n_in,
                              void* d_out, int out_size, void* d_ws,
                              size_t ws_size, hipStream_t stream) {
  const float* x     = (const float*)d_in[0];
  const float* W_qkv = (const float*)d_in[1];
  const float* b_qkv = (const float*)d_in[2];
  const float* W_out = (const float*)d_in[3];
  const float* b_out = (const float*)d_in[4];
  float* out = (float*)d_out;

  const size_t NX = (size_t)4 * SEQ_T * D_MODEL;        // 4,194,304
  unsigned short* xb   = (unsigned short*)d_ws;          // [8192][512]
  unsigned short* Wqkt = xb + NX;                        // [1536][512]
  unsigned short* Wot  = Wqkt + (size_t)1536 * 512;      // [512][512]
  unsigned short* Qtb  = Wot + (size_t)512 * 512;        // [bh][d][t]
  unsigned short* Kb   = Qtb + NX;                       // [bh][t][d]
  unsigned short* Vtb  = Kb + NX;                        // [bh][dv][t]
  unsigned short* AOb  = Vtb + NX;                       // [8192][512]

  prep_kernel<<<2304, 256, 0, stream>>>(x, W_qkv, W_out, xb, Wqkt, Wot);
  gemm_qkv_mfma<<<dim3(64, 12), 256, 0, stream>>>(xb, Wqkt, b_qkv, Qtb, Kb,
                                                  Vtb);
  attn_mfma6<<<dim3(512), 256, 0, stream>>>(Qtb, Kb, Vtb, AOb);
  gemm_out_mfma<<<dim3(128, 4), 256, 0, stream>>>(AOb, Wot, b_out, out);
}

// Round 4
// 147.342 us; speedup vs baseline: 1.0028x; 1.0028x over previous
//
#include <hip/hip_runtime.h>
#include <cstdint>
#include <cstddef>

#define D_MODEL 512
#define SEQ_T 2048
#define NHEADS 8
#define HDIM 64

typedef __attribute__((ext_vector_type(8))) short bf16x8;
typedef __attribute__((ext_vector_type(4))) float f32x4;
typedef __attribute__((ext_vector_type(16))) float f32x16;
typedef __attribute__((ext_vector_type(2))) unsigned int uint2v;

__device__ __forceinline__ unsigned short f2bf(float f) {
  unsigned int u = __float_as_uint(f);
  u += 0x7FFFu + ((u >> 16) & 1u);
  return (unsigned short)(u >> 16);
}

// pack two f32 -> two bf16 in one uint (round via +0x8000, v_perm)
__device__ __forceinline__ unsigned int pack_bf16(float lo, float hi) {
  unsigned int a = __float_as_uint(lo) + 0x8000u;
  unsigned int b = __float_as_uint(hi) + 0x8000u;
  return __builtin_amdgcn_perm(b, a, 0x07060302u);
}

// CDNA4 half-wave exchange via BUILTIN (inline-asm "+v","+v" form mangled
// dataflow -> NaN; builtin returns {a',b'} with a'={a.lo,b.lo}, b'={a.hi,b.hi})
__device__ __forceinline__ void plswap(unsigned int& a, unsigned int& b) {
  uint2v r = __builtin_amdgcn_permlane32_swap(a, b, false, false);
  a = r[0];
  b = r[1];
}

// Q pre-scaled by 1/sqrt(64) * log2(e) so softmax runs in exp2 domain.
#define QSCALE 0.18033688011112043f
// fixed softmax shift: p = exp2(s - SSHIFT); common factor cancels in O/l.
#define SSHIFT 16.0f

// async global->LDS, 16B per lane. LDS dest = wave-uniform base + lane*16.
__device__ __forceinline__ void async_lds16(const unsigned short* g,
                                            unsigned short* l) {
  __builtin_amdgcn_global_load_lds(
      (const __attribute__((address_space(1))) void*)g,
      (__attribute__((address_space(3))) void*)l, 16, 0, 0);
}

// ---------------------------------------------------------------------------
// Fused prep: [0,2048) cast x -> bf16; [2048,2240) transpose W_qkv;
// [2240,2304) transpose W_out.
// ---------------------------------------------------------------------------
__global__ __launch_bounds__(256) void prep_kernel(
    const float* __restrict__ x, const float* __restrict__ W_qkv,
    const float* __restrict__ W_out, unsigned short* __restrict__ xb,
    unsigned short* __restrict__ Wqkt, unsigned short* __restrict__ Wot) {
  __shared__ float tile[64][65];
  const int bid = blockIdx.x;
  if (bid < 2048) {
    int i = (bid * 256 + threadIdx.x) * 8;
    float4 a = *(const float4*)(x + i);
    float4 b = *(const float4*)(x + i + 4);
    ushort4 lo = {f2bf(a.x), f2bf(a.y), f2bf(a.z), f2bf(a.w)};
    ushort4 hi = {f2bf(b.x), f2bf(b.y), f2bf(b.z), f2bf(b.w)};
    *(ushort4*)(xb + i) = lo;
    *(ushort4*)(xb + i + 4) = hi;
    return;
  }
  const float* src;
  unsigned short* dst;
  int R = 512, C, c0, r0;
  if (bid < 2048 + 192) {
    int t = bid - 2048;
    C = 1536; c0 = (t % 24) * 64; r0 = (t / 24) * 64;
    src = W_qkv; dst = Wqkt;
  } else {
    int t = bid - 2240;
    C = 512; c0 = (t & 7) * 64; r0 = (t >> 3) * 64;
    src = W_out; dst = Wot;
  }
  for (int i = threadIdx.x; i < 64 * 64; i += 256) {
    int r = i >> 6, c = i & 63;
    tile[r][c] = src[(size_t)(r0 + r) * C + c0 + c];
  }
  __syncthreads();
  for (int i = threadIdx.x; i < 64 * 64; i += 256) {
    int c = i >> 6, r = i & 63;
    dst[(size_t)(c0 + c) * R + r0 + r] = f2bf(tile[r][c]);
  }
}

// ---------------------------------------------------------------------------
// Kernel 1: QKV projection, bf16 MFMA. 128x128 tile, BK=64 (8 K-iters),
// XOR-swizzled LDS (16B chunk ^= row&7) -> conflict-free b128 fragment reads.
// Epilogue: Q -> bf16 [bh][d][t] TRANSPOSED packed ushort4 (pre-scaled);
// V -> bf16 [bh][dv][t] packed ushort4; K -> bf16 [bh][t][d] scalar.
// ---------------------------------------------------------------------------
__global__ __launch_bounds__(256) void gemm_qkv_mfma(
    const unsigned short* __restrict__ xb, const unsigned short* __restrict__ Wt,
    const float* __restrict__ bias, unsigned short* __restrict__ Qtb,
    unsigned short* __restrict__ Kb, unsigned short* __restrict__ Vtb) {
  __shared__ unsigned short As[128 * 64];
  __shared__ unsigned short Bs[128 * 64];
  const int tid = threadIdx.x;
  const int w = tid >> 6, lane = tid & 63;
  const int quad = lane >> 4, l15 = lane & 15;
  const int wm = w >> 1, wn = w & 1;
  const int m0 = blockIdx.x * 128, n0 = blockIdx.y * 128;

  const int srow = tid >> 3;                   // 0..31
  const int schunk = (tid & 7) ^ (srow & 7);   // logical chunk loaded
  const unsigned short* ga = xb + (size_t)(m0 + srow) * 512 + schunk * 8;
  const unsigned short* gb = Wt + (size_t)(n0 + srow) * 512 + schunk * 8;
  unsigned short* lA = As + tid * 8;
  unsigned short* lB = Bs + tid * 8;

  f32x4 acc[4][4] = {};
  for (int k0 = 0; k0 < 512; k0 += 64) {
#pragma unroll
    for (int rr = 0; rr < 4; ++rr) {
      async_lds16(ga + (size_t)rr * 32 * 512 + k0, lA + rr * 2048);
      async_lds16(gb + (size_t)rr * 32 * 512 + k0, lB + rr * 2048);
    }
    __syncthreads();
    bf16x8 af[4][2], bfr[4][2];
#pragma unroll
    for (int mb = 0; mb < 4; ++mb) {
      int row = wm * 64 + mb * 16 + l15;
#pragma unroll
      for (int kk = 0; kk < 2; ++kk) {
        int slot = (kk * 4 + quad) ^ (row & 7);
        af[mb][kk] = *(const bf16x8*)&As[row * 64 + slot * 8];
      }
    }
#pragma unroll
    for (int nb = 0; nb < 4; ++nb) {
      int row = wn * 64 + nb * 16 + l15;
#pragma unroll
      for (int kk = 0; kk < 2; ++kk) {
        int slot = (kk * 4 + quad) ^ (row & 7);
        bfr[nb][kk] = *(const bf16x8*)&Bs[row * 64 + slot * 8];
      }
    }
#pragma unroll
    for (int mb = 0; mb < 4; ++mb)
#pragma unroll
      for (int nb = 0; nb < 4; ++nb) {
        acc[mb][nb] = __builtin_amdgcn_mfma_f32_16x16x32_bf16(
            af[mb][0], bfr[nb][0], acc[mb][nb], 0, 0, 0);
        acc[mb][nb] = __builtin_amdgcn_mfma_f32_16x16x32_bf16(
            af[mb][1], bfr[nb][1], acc[mb][nb], 0, 0, 0);
      }
    __syncthreads();
  }

  const int cbase = n0 + wn * 64;
  const int three = cbase >> 9;          // 0:Q 1:K 2:V
  const int h = (cbase >> 6) & 7;
  const int bh = ((m0 >> 11) << 3) + h;
  const int t0 = (m0 & 2047) + wm * 64;
  float bv[4];
#pragma unroll
  for (int nb = 0; nb < 4; ++nb) bv[nb] = bias[cbase + nb * 16 + l15];

  if (three == 0) {
    // Q transposed [bh][d][t], pre-scaled, packed along t
#pragma unroll
    for (int mb = 0; mb < 4; ++mb)
#pragma unroll
      for (int nb = 0; nb < 4; ++nb) {
        int trow = t0 + mb * 16 + quad * 4;
        ushort4 v = {f2bf((acc[mb][nb][0] + bv[nb]) * QSCALE),
                     f2bf((acc[mb][nb][1] + bv[nb]) * QSCALE),
                     f2bf((acc[mb][nb][2] + bv[nb]) * QSCALE),
                     f2bf((acc[mb][nb][3] + bv[nb]) * QSCALE)};
        *(ushort4*)(Qtb + ((size_t)bh * HDIM + nb * 16 + l15) * SEQ_T + trow) = v;
      }
  } else if (three == 2) {
    // V transposed [bh][dv][t], packed along t
#pragma unroll
    for (int mb = 0; mb < 4; ++mb)
#pragma unroll
      for (int nb = 0; nb < 4; ++nb) {
        int trow = t0 + mb * 16 + quad * 4;
        ushort4 v = {f2bf(acc[mb][nb][0] + bv[nb]), f2bf(acc[mb][nb][1] + bv[nb]),
                     f2bf(acc[mb][nb][2] + bv[nb]), f2bf(acc[mb][nb][3] + bv[nb])};
        *(ushort4*)(Vtb + ((size_t)bh * HDIM + nb * 16 + l15) * SEQ_T + trow) = v;
      }
  } else {
    // K row-major [bh][t][d] (required for attn A-fragment contiguity)
#pragma unroll
    for (int mb = 0; mb < 4; ++mb)
#pragma unroll
      for (int nb = 0; nb < 4; ++nb)
#pragma unroll
        for (int r = 0; r < 4; ++r) {
          int trow = t0 + mb * 16 + quad * 4 + r;
          Kb[((size_t)bh * SEQ_T + trow) * HDIM + nb * 16 + l15] =
              f2bf(acc[mb][nb][r] + bv[nb]);
        }
  }
}

// ---------------------------------------------------------------------------
// Kernel 2 (v7): causal flash attention on 32x32x16 MFMAs.
//  - 128-query blocks (4 waves x 32 q), 512 blocks = 2/CU; CU-slot pairs
//    (15-k, k) give exactly 34 key-tiles per CU; longest-first dispatch
//  - K/V staging via global_load_lds with pre-swizzled SOURCE (m173 pattern):
//    no ds_write instructions, no VGPR round-trip, double-buffered
//  - P redistribution fully in-register via __builtin_amdgcn_permlane32_swap
//    (no Pt LDS at all); l via VALU adds + one __shfl_xor
//  - s_setprio(1) around MFMA clusters (T5)
//  - fixed-shift softmax p = exp2(s-16)
// ---------------------------------------------------------------------------
__global__ __launch_bounds__(256, 2) void attn_mfma7(
    const unsigned short* __restrict__ Qtb, const unsigned short* __restrict__ Kb,
    const unsigned short* __restrict__ Vtb, unsigned short* __restrict__ AOb) {
  __shared__ __align__(16) unsigned short Ks[2][64 * 64];
  __shared__ __align__(16) unsigned short Vs[2][64 * 64];
  const int tid = threadIdx.x;
  const int w = tid >> 6, lane = tid & 63;
  const int l31 = lane & 31, h = lane >> 5;
  const int r7l = lane & 7;

  // balanced (bh, qt2) mapping: co-resident pair sums to 34 key-tiles
  const int bid = blockIdx.x;
  const int xcd = bid & 7;
  const int j = bid >> 3;            // 0..63
  const int c = j & 31, g = j >> 5;  // CU slot within XCD, co-res slot
  const int kslot = c >> 2;
  const int bh = xcd + 8 * (c & 3);
  const int qt2 = g ? kslot : (15 - kslot);
  const int nmain = 2 * qt2;         // full (unmasked) 64-key tiles

  const unsigned short* kbase = Kb + (size_t)bh * SEQ_T * HDIM;
  const unsigned short* vbase = Vtb + (size_t)bh * HDIM * SEQ_T;
  const int sr = tid >> 3;             // staging row 0..31
  const int lc = tid & 7;              // dest 16B chunk slot
  const int sw8 = (lc ^ (sr & 7)) * 8; // pre-swizzled SOURCE chunk offset

  // stage tile kt into buffer b: 4 global_load_lds DMAs per thread.
  // dest is linear (tid*16B); source chunk pre-swizzled so LDS slot s of
  // row r holds logical chunk s^(r&7)  [rule #21: linear dest + inv-swz src]
  auto stage = [&](int b, int kt) {
    const unsigned short* kp = kbase + (size_t)(kt * 64 + sr) * 64 + sw8;
    async_lds16(kp, &Ks[b][tid * 8]);
    async_lds16(kp + 32 * 64, &Ks[b][2048 + tid * 8]);
    const unsigned short* vp = vbase + (size_t)sr * SEQ_T + kt * 64 + sw8;
    async_lds16(vp, &Vs[b][tid * 8]);
    async_lds16(vp + (size_t)32 * SEQ_T, &Vs[b][2048 + tid * 8]);
  };

  // Q B-fragments: qf[c] = Q[d = c*16 + h*8 + j][q = qglob]
  const int qglob = qt2 * 128 + w * 32 + l31;
  bf16x8 qf[4];
  {
    unsigned short qraw[32];
    const unsigned short* qp =
        Qtb + ((size_t)bh * HDIM + h * 8) * SEQ_T + qglob;
#pragma unroll
    for (int cc = 0; cc < 4; ++cc)
#pragma unroll
      for (int jj = 0; jj < 8; ++jj)
        qraw[cc * 8 + jj] = qp[(size_t)(cc * 16 + jj) * SEQ_T];
#pragma unroll
    for (int cc = 0; cc < 4; ++cc) qf[cc] = *(const bf16x8*)(qraw + cc * 8);
  }

  f32x16 O0 = {0.f, 0.f, 0.f, 0.f, 0.f, 0.f, 0.f, 0.f,
               0.f, 0.f, 0.f, 0.f, 0.f, 0.f, 0.f, 0.f};
  f32x16 O1 = O0;
  float l_acc = 0.f;

  // tile compute: QK^T (8 MFMA) -> exp2/pack -> permlane swaps -> PV (8 MFMA)
  auto tile_compute = [&](int cur, int lim, bool masked) {
    f32x16 S0 = {0.f, 0.f, 0.f, 0.f, 0.f, 0.f, 0.f, 0.f,
                 0.f, 0.f, 0.f, 0.f, 0.f, 0.f, 0.f, 0.f};
    f32x16 S1 = S0;
    __builtin_amdgcn_s_setprio(1);
#pragma unroll
    for (int cc = 0; cc < 4; ++cc) {
      const int slot = ((cc << 1) | h) ^ r7l;
      const bf16x8 k0 = *(const bf16x8*)&Ks[cur][l31 * 64 + slot * 8];
      const bf16x8 k1 = *(const bf16x8*)&Ks[cur][(32 + l31) * 64 + slot * 8];
      S0 = __builtin_amdgcn_mfma_f32_32x32x16_bf16(k0, qf[cc], S0, 0, 0, 0);
      S1 = __builtin_amdgcn_mfma_f32_32x32x16_bf16(k1, qf[cc], S1, 0, 0, 0);
    }
    __builtin_amdgcn_s_setprio(0);
    // lane holds S[key = kl][q = l31]; kl = (r&3)+8*(r>>2)+4h (S0), +32 (S1).
    unsigned int pk0[8], pk1[8];
#pragma unroll
    for (int m = 0; m < 8; ++m) {
      float p0 = __builtin_amdgcn_exp2f(S0[2 * m] - SSHIFT);
      float p1 = __builtin_amdgcn_exp2f(S0[2 * m + 1] - SSHIFT);
      float p2 = __builtin_amdgcn_exp2f(S1[2 * m] - SSHIFT);
      float p3 = __builtin_amdgcn_exp2f(S1[2 * m + 1] - SSHIFT);
      if (masked) {
        const int r0 = 2 * m, r1 = 2 * m + 1;
        const int kl0 = (r0 & 3) + 8 * (r0 >> 2) + 4 * h;
        const int kl1 = (r1 & 3) + 8 * (r1 >> 2) + 4 * h;
        p0 = (kl0 > lim) ? 0.f : p0;
        p1 = (kl1 > lim) ? 0.f : p1;
        p2 = (kl0 + 32 > lim) ? 0.f : p2;
        p3 = (kl1 + 32 > lim) ? 0.f : p3;
      }
      l_acc += (p0 + p1) + (p2 + p3);
      pk0[m] = pack_bf16(p0, p1);
      pk1[m] = pack_bf16(p2, p3);
    }
    // redistribute: for chunk pair tp: swap(pk[4tp+i], pk[4tp+2+i]) i=0,1
    // (verified vs 32x32 C-layout: reader (l31,h_r) chunk t frag =
    //  {h0.pk[m0], h0.pk[m0+1], h1.pk[m0], h1.pk[m0+1]}, m0=4(t&1)+2h_r)
#pragma unroll
    for (int tp = 0; tp < 2; ++tp) {
      plswap(pk0[4 * tp + 0], pk0[4 * tp + 2]);
      plswap(pk0[4 * tp + 1], pk0[4 * tp + 3]);
      plswap(pk1[4 * tp + 0], pk1[4 * tp + 2]);
      plswap(pk1[4 * tp + 1], pk1[4 * tp + 3]);
    }
    // PV: chunk t = 2*kb + tp covers keys 16t..16t+15
#pragma unroll
    for (int kb = 0; kb < 2; ++kb)
#pragma unroll
      for (int tp = 0; tp < 2; ++tp) {
        const int t = 2 * kb + tp;
        uint4 wv;
        if (kb == 0)
          wv = (uint4){pk0[4 * tp + 0], pk0[4 * tp + 1], pk0[4 * tp + 2],
                       pk0[4 * tp + 3]};
        else
          wv = (uint4){pk1[4 * tp + 0], pk1[4 * tp + 1], pk1[4 * tp + 2],
                       pk1[4 * tp + 3]};
        const bf16x8 pb = *(const bf16x8*)&wv;
        const int slot = ((t << 1) | h) ^ r7l;
        const bf16x8 v0 = *(const bf16x8*)&Vs[cur][l31 * 64 + slot * 8];
        const bf16x8 v1 = *(const bf16x8*)&Vs[cur][(32 + l31) * 64 + slot * 8];
        __builtin_amdgcn_s_setprio(1);
        O0 = __builtin_amdgcn_mfma_f32_32x32x16_bf16(v0, pb, O0, 0, 0, 0);
        O1 = __builtin_amdgcn_mfma_f32_32x32x16_bf16(v1, pb, O1, 0, 0, 0);
        __builtin_amdgcn_s_setprio(0);
      }
  };

  // prologue: stage tile 0 into buffer 0 (vmcnt(0) implied by barrier)
  stage(0, 0);
  __syncthreads();

  // ---- main loop: fully-unmasked tiles, branch-free ----
  for (int i = 0; i < nmain; ++i) {
    const int cur = i & 1;
    stage(cur ^ 1, i + 1);   // DMA for next tile overlaps this tile's compute
    tile_compute(cur, 0, false);
    __syncthreads();         // drains vmcnt -> buf nxt ready for all waves
  }

  // ---- diagonal tile A (kt = nmain): keys 128*qt2 .. +63 ----
  {
    const int cur = nmain & 1;
    stage(cur ^ 1, nmain + 1);
    tile_compute(cur, w * 32 + l31, true);
    __syncthreads();
  }

  // ---- diagonal tile B (kt = nmain+1): keys +64..+127; waves 0,1 are
  // fully masked (all keys > all their queries) -> skip (wave-uniform) ----
  if (w >= 2) {
    const int cur = (nmain + 1) & 1;
    tile_compute(cur, w * 32 + l31 - 64, true);
  }

  // ---- reduce l across the two half-waves holding column q ----
  l_acc += __shfl_xor(l_acc, 32, 64);
  // safety clamp: any residual l=0 bug shows as finite error, not NaN
  const float inv = 1.0f / fmaxf(l_acc, 1e-30f);
  const int bb = bh >> 3, hh = bh & 7;
  unsigned short* dst = AOb + ((size_t)bb * SEQ_T + qglob) * D_MODEL + (hh << 6);
#pragma unroll
  for (int rg = 0; rg < 4; ++rg) {
    ushort4 o0 = {f2bf(O0[4 * rg + 0] * inv), f2bf(O0[4 * rg + 1] * inv),
                  f2bf(O0[4 * rg + 2] * inv), f2bf(O0[4 * rg + 3] * inv)};
    *(ushort4*)(dst + 8 * rg + 4 * h) = o0;
    ushort4 o1 = {f2bf(O1[4 * rg + 0] * inv), f2bf(O1[4 * rg + 1] * inv),
                  f2bf(O1[4 * rg + 2] * inv), f2bf(O1[4 * rg + 3] * inv)};
    *(ushort4*)(dst + 32 + 8 * rg + 4 * h) = o1;
  }
}

// ---------------------------------------------------------------------------
// Kernel 3: output projection, bf16 MFMA. 64x128 tile (512 blocks, 2/CU),
// BK=64 swizzled. AOb[8192][512] @ Wot[512][512]^T + b -> fp32 out.
// ---------------------------------------------------------------------------
__global__ __launch_bounds__(256) void gemm_out_mfma(
    const unsigned short* __restrict__ AOb, const unsigned short* __restrict__ Wot,
    const float* __restrict__ bias, float* __restrict__ out) {
  __shared__ unsigned short As[64 * 64];
  __shared__ unsigned short Bs[128 * 64];
  const int tid = threadIdx.x;
  const int w = tid >> 6, lane = tid & 63;
  const int quad = lane >> 4, l15 = lane & 15;
  const int m0 = blockIdx.x * 64, n0 = blockIdx.y * 128;

  const int srow = tid >> 3;
  const int schunk = (tid & 7) ^ (srow & 7);
  const unsigned short* ga = AOb + (size_t)(m0 + srow) * 512 + schunk * 8;
  const unsigned short* gb = Wot + (size_t)(n0 + srow) * 512 + schunk * 8;
  unsigned short* lA = As + tid * 8;
  unsigned short* lB = Bs + tid * 8;

  f32x4 acc[4][2] = {};
  for (int k0 = 0; k0 < 512; k0 += 64) {
#pragma unroll
    for (int rr = 0; rr < 2; ++rr)
      async_lds16(ga + (size_t)rr * 32 * 512 + k0, lA + rr * 2048);
#pragma unroll
    for (int rr = 0; rr < 4; ++rr)
      async_lds16(gb + (size_t)rr * 32 * 512 + k0, lB + rr * 2048);
    __syncthreads();
    bf16x8 af[4][2], bfr[2][2];
#pragma unroll
    for (int mb = 0; mb < 4; ++mb) {
      int row = mb * 16 + l15;
#pragma unroll
      for (int kk = 0; kk < 2; ++kk) {
        int slot = (kk * 4 + quad) ^ (row & 7);
        af[mb][kk] = *(const bf16x8*)&As[row * 64 + slot * 8];
      }
    }
#pragma unroll
    for (int nb = 0; nb < 2; ++nb) {
      int row = w * 32 + nb * 16 + l15;
#pragma unroll
      for (int kk = 0; kk < 2; ++kk) {
        int slot = (kk * 4 + quad) ^ (row & 7);
        bfr[nb][kk] = *(const bf16x8*)&Bs[row * 64 + slot * 8];
      }
    }
#pragma unroll
    for (int mb = 0; mb < 4; ++mb)
#pragma unroll
      for (int nb = 0; nb < 2; ++nb) {
        acc[mb][nb] = __builtin_amdgcn_mfma_f32_16x16x32_bf16(
            af[mb][0], bfr[nb][0], acc[mb][nb], 0, 0, 0);
        acc[mb][nb] = __builtin_amdgcn_mfma_f32_16x16x32_bf16(
            af[mb][1], bfr[nb][1], acc[mb][nb], 0, 0, 0);
      }
    __syncthreads();
  }

  const int cbase = n0 + w * 32;
  float bv[2];
#pragma unroll
  for (int nb = 0; nb < 2; ++nb) bv[nb] = bias[cbase + nb * 16 + l15];
#pragma unroll
  for (int mb = 0; mb < 4; ++mb)
#pragma unroll
    for (int nb = 0; nb < 2; ++nb)
#pragma unroll
      for (int r = 0; r < 4; ++r)
        out[(size_t)(m0 + mb * 16 + quad * 4 + r) * 512 + cbase + nb * 16 +
            l15] = acc[mb][nb][r] + bv[nb];
}

// ---------------------------------------------------------------------------
extern "C" void kernel_launch(void* const* d_in, const int* in_sizes, int n_in,
                              void* d_out, int out_size, void* d_ws,
                              size_t ws_size, hipStream_t stream) {
  const float* x     = (const float*)d_in[0];
  const float* W_qkv = (const float*)d_in[1];
  const float* b_qkv = (const float*)d_in[2];
  const float* W_out = (const float*)d_in[3];
  const float* b_out = (const float*)d_in[4];
  float* out = (float*)d_out;

  const size_t NX = (size_t)4 * SEQ_T * D_MODEL;        // 4,194,304
  unsigned short* xb   = (unsigned short*)d_ws;          // [8192][512]
  unsigned short* Wqkt = xb + NX;                        // [1536][512]
  unsigned short* Wot  = Wqkt + (size_t)1536 * 512;      // [512][512]
  unsigned short* Qtb  = Wot + (size_t)512 * 512;        // [bh][d][t]
  unsigned short* Kb   = Qtb + NX;                       // [bh][t][d]
  unsigned short* Vtb  = Kb + NX;                        // [bh][dv][t]
  unsigned short* AOb  = Vtb + NX;                       // [8192][512]

  prep_kernel<<<2304, 256, 0, stream>>>(x, W_qkv, W_out, xb, Wqkt, Wot);
  gemm_qkv_mfma<<<dim3(64, 12), 256, 0, stream>>>(xb, Wqkt, b_qkv, Qtb, Kb,
                                                  Vtb);
  attn_mfma7<<<dim3(512), 256, 0, stream>>>(Qtb, Kb, Vtb, AOb);
  gemm_out_mfma<<<dim3(128, 4), 256, 0, stream>>>(AOb, Wot, b_out, out);
}

// Round 6
// 137.816 us; speedup vs baseline: 1.0722x; 1.0691x over previous
//
#include <hip/hip_runtime.h>
#include <cstdint>
#include <cstddef>

#define D_MODEL 512
#define SEQ_T 2048
#define NHEADS 8
#define HDIM 64

typedef __attribute__((ext_vector_type(8))) short bf16x8;
typedef __attribute__((ext_vector_type(4))) float f32x4;
typedef __attribute__((ext_vector_type(16))) float f32x16;
typedef __attribute__((ext_vector_type(2))) unsigned int uint2v;

__device__ __forceinline__ unsigned short f2bf(float f) {
  unsigned int u = __float_as_uint(f);
  u += 0x7FFFu + ((u >> 16) & 1u);
  return (unsigned short)(u >> 16);
}

// pack two f32 -> two bf16 in one uint (round via +0x8000, v_perm)
__device__ __forceinline__ unsigned int pack_bf16(float lo, float hi) {
  unsigned int a = __float_as_uint(lo) + 0x8000u;
  unsigned int b = __float_as_uint(hi) + 0x8000u;
  return __builtin_amdgcn_perm(b, a, 0x07060302u);
}

// CDNA4 half-wave exchange via BUILTIN: a'={a.lo,b.lo}, b'={a.hi,b.hi}
__device__ __forceinline__ void plswap(unsigned int& a, unsigned int& b) {
  uint2v r = __builtin_amdgcn_permlane32_swap(a, b, false, false);
  a = r[0];
  b = r[1];
}

// Q pre-scaled by 1/sqrt(64) * log2(e) so softmax runs in exp2 domain.
#define QSCALE 0.18033688011112043f
// fixed softmax shift: p = exp2(s - SSHIFT); common factor cancels in O/l.
// (fixed shift => partial O/l over disjoint key sets are directly addable)
#define SSHIFT 16.0f

// async global->LDS, 16B per lane. LDS dest = wave-uniform base + lane*16.
__device__ __forceinline__ void async_lds16(const unsigned short* g,
                                            unsigned short* l) {
  __builtin_amdgcn_global_load_lds(
      (const __attribute__((address_space(1))) void*)g,
      (__attribute__((address_space(3))) void*)l, 16, 0, 0);
}

// ---------------------------------------------------------------------------
// Fused prep: [0,2048) cast x -> bf16; [2048,2240) transpose W_qkv;
// [2240,2304) transpose W_out.
// ---------------------------------------------------------------------------
__global__ __launch_bounds__(256) void prep_kernel(
    const float* __restrict__ x, const float* __restrict__ W_qkv,
    const float* __restrict__ W_out, unsigned short* __restrict__ xb,
    unsigned short* __restrict__ Wqkt, unsigned short* __restrict__ Wot) {
  __shared__ float tile[64][65];
  const int bid = blockIdx.x;
  if (bid < 2048) {
    int i = (bid * 256 + threadIdx.x) * 8;
    float4 a = *(const float4*)(x + i);
    float4 b = *(const float4*)(x + i + 4);
    ushort4 lo = {f2bf(a.x), f2bf(a.y), f2bf(a.z), f2bf(a.w)};
    ushort4 hi = {f2bf(b.x), f2bf(b.y), f2bf(b.z), f2bf(b.w)};
    *(ushort4*)(xb + i) = lo;
    *(ushort4*)(xb + i + 4) = hi;
    return;
  }
  const float* src;
  unsigned short* dst;
  int R = 512, C, c0, r0;
  if (bid < 2048 + 192) {
    int t = bid - 2048;
    C = 1536; c0 = (t % 24) * 64; r0 = (t / 24) * 64;
    src = W_qkv; dst = Wqkt;
  } else {
    int t = bid - 2240;
    C = 512; c0 = (t & 7) * 64; r0 = (t >> 3) * 64;
    src = W_out; dst = Wot;
  }
  for (int i = threadIdx.x; i < 64 * 64; i += 256) {
    int r = i >> 6, c = i & 63;
    tile[r][c] = src[(size_t)(r0 + r) * C + c0 + c];
  }
  __syncthreads();
  for (int i = threadIdx.x; i < 64 * 64; i += 256) {
    int c = i >> 6, r = i & 63;
    dst[(size_t)(c0 + c) * R + r0 + r] = f2bf(tile[r][c]);
  }
}

// ---------------------------------------------------------------------------
// Kernel 1: QKV projection, bf16 MFMA. 128x128 tile, BK=64 (8 K-iters),
// XOR-swizzled LDS (16B chunk ^= row&7) -> conflict-free b128 fragment reads.
// Epilogue: Q -> bf16 [bh][d][t] TRANSPOSED packed ushort4 (pre-scaled);
// V -> bf16 [bh][dv][t] packed ushort4; K -> bf16 [bh][t][d] scalar.
// ---------------------------------------------------------------------------
__global__ __launch_bounds__(256) void gemm_qkv_mfma(
    const unsigned short* __restrict__ xb, const unsigned short* __restrict__ Wt,
    const float* __restrict__ bias, unsigned short* __restrict__ Qtb,
    unsigned short* __restrict__ Kb, unsigned short* __restrict__ Vtb) {
  __shared__ unsigned short As[128 * 64];
  __shared__ unsigned short Bs[128 * 64];
  const int tid = threadIdx.x;
  const int w = tid >> 6, lane = tid & 63;
  const int quad = lane >> 4, l15 = lane & 15;
  const int wm = w >> 1, wn = w & 1;
  const int m0 = blockIdx.x * 128, n0 = blockIdx.y * 128;

  const int srow = tid >> 3;                   // 0..31
  const int schunk = (tid & 7) ^ (srow & 7);   // logical chunk loaded
  const unsigned short* ga = xb + (size_t)(m0 + srow) * 512 + schunk * 8;
  const unsigned short* gb = Wt + (size_t)(n0 + srow) * 512 + schunk * 8;
  unsigned short* lA = As + tid * 8;
  unsigned short* lB = Bs + tid * 8;

  f32x4 acc[4][4] = {};
  for (int k0 = 0; k0 < 512; k0 += 64) {
#pragma unroll
    for (int rr = 0; rr < 4; ++rr) {
      async_lds16(ga + (size_t)rr * 32 * 512 + k0, lA + rr * 2048);
      async_lds16(gb + (size_t)rr * 32 * 512 + k0, lB + rr * 2048);
    }
    __syncthreads();
    bf16x8 af[4][2], bfr[4][2];
#pragma unroll
    for (int mb = 0; mb < 4; ++mb) {
      int row = wm * 64 + mb * 16 + l15;
#pragma unroll
      for (int kk = 0; kk < 2; ++kk) {
        int slot = (kk * 4 + quad) ^ (row & 7);
        af[mb][kk] = *(const bf16x8*)&As[row * 64 + slot * 8];
      }
    }
#pragma unroll
    for (int nb = 0; nb < 4; ++nb) {
      int row = wn * 64 + nb * 16 + l15;
#pragma unroll
      for (int kk = 0; kk < 2; ++kk) {
        int slot = (kk * 4 + quad) ^ (row & 7);
        bfr[nb][kk] = *(const bf16x8*)&Bs[row * 64 + slot * 8];
      }
    }
#pragma unroll
    for (int mb = 0; mb < 4; ++mb)
#pragma unroll
      for (int nb = 0; nb < 4; ++nb) {
        acc[mb][nb] = __builtin_amdgcn_mfma_f32_16x16x32_bf16(
            af[mb][0], bfr[nb][0], acc[mb][nb], 0, 0, 0);
        acc[mb][nb] = __builtin_amdgcn_mfma_f32_16x16x32_bf16(
            af[mb][1], bfr[nb][1], acc[mb][nb], 0, 0, 0);
      }
    __syncthreads();
  }

  const int cbase = n0 + wn * 64;
  const int three = cbase >> 9;          // 0:Q 1:K 2:V
  const int h = (cbase >> 6) & 7;
  const int bh = ((m0 >> 11) << 3) + h;
  const int t0 = (m0 & 2047) + wm * 64;
  float bv[4];
#pragma unroll
  for (int nb = 0; nb < 4; ++nb) bv[nb] = bias[cbase + nb * 16 + l15];

  if (three == 0) {
    // Q transposed [bh][d][t], pre-scaled, packed along t
#pragma unroll
    for (int mb = 0; mb < 4; ++mb)
#pragma unroll
      for (int nb = 0; nb < 4; ++nb) {
        int trow = t0 + mb * 16 + quad * 4;
        ushort4 v = {f2bf((acc[mb][nb][0] + bv[nb]) * QSCALE),
                     f2bf((acc[mb][nb][1] + bv[nb]) * QSCALE),
                     f2bf((acc[mb][nb][2] + bv[nb]) * QSCALE),
                     f2bf((acc[mb][nb][3] + bv[nb]) * QSCALE)};
        *(ushort4*)(Qtb + ((size_t)bh * HDIM + nb * 16 + l15) * SEQ_T + trow) = v;
      }
  } else if (three == 2) {
    // V transposed [bh][dv][t], packed along t
#pragma unroll
    for (int mb = 0; mb < 4; ++mb)
#pragma unroll
      for (int nb = 0; nb < 4; ++nb) {
        int trow = t0 + mb * 16 + quad * 4;
        ushort4 v = {f2bf(acc[mb][nb][0] + bv[nb]), f2bf(acc[mb][nb][1] + bv[nb]),
                     f2bf(acc[mb][nb][2] + bv[nb]), f2bf(acc[mb][nb][3] + bv[nb])};
        *(ushort4*)(Vtb + ((size_t)bh * HDIM + nb * 16 + l15) * SEQ_T + trow) = v;
      }
  } else {
    // K row-major [bh][t][d] (required for attn A-fragment contiguity)
#pragma unroll
    for (int mb = 0; mb < 4; ++mb)
#pragma unroll
      for (int nb = 0; nb < 4; ++nb)
#pragma unroll
        for (int r = 0; r < 4; ++r) {
          int trow = t0 + mb * 16 + quad * 4 + r;
          Kb[((size_t)bh * SEQ_T + trow) * HDIM + nb * 16 + l15] =
              f2bf(acc[mb][nb][r] + bv[nb]);
        }
  }
}

// ---------------------------------------------------------------------------
// Kernel 2 (v8): causal flash attention, 32x32x16 MFMAs, INTRINSIC balance.
//  - 512 blocks of 4 waves; block (bh, pr) processes q-tile pr THEN q-tile
//    31-pr (64 queries each): 33 key-tiles / 17 steps per block, IDENTICAL
//    for every block -> balanced regardless of HW dispatch order.
//  - waves: qhalf = w&1 (which 32 queries), ks = w>>1 (even/odd key-tiles).
//    Fixed-shift softmax => partial (O,l) over disjoint keys are addable;
//    parity halves combine via conflict-free LDS exchange once per phase.
//  - per step: stage next PAIR of tiles (dbuf), each wave computes its
//    parity's tile; ONE barrier per step (~19/block vs 34 in v7).
//  - inner tile math identical to v7 (permlane P-redistr, DMA staging).
// ---------------------------------------------------------------------------
__global__ __launch_bounds__(256, 2) void attn_mfma8(
    const unsigned short* __restrict__ Qtb, const unsigned short* __restrict__ Kb,
    const unsigned short* __restrict__ Vtb, unsigned short* __restrict__ AOb) {
  __shared__ __align__(16) unsigned short Kp[2][2][64 * 64];  // [buf][parity]
  __shared__ __align__(16) unsigned short Vp[2][2][64 * 64];
  const int tid = threadIdx.x;
  const int w = tid >> 6, lane = tid & 63;
  const int l31 = lane & 31, h = lane >> 5;
  const int r7l = lane & 7;
  const int qhalf = w & 1, ks = w >> 1;

  const int bid = blockIdx.x;
  const int bh = bid & 31;
  const int pr = bid >> 5;  // 0..15

  const unsigned short* kbase = Kb + (size_t)bh * SEQ_T * HDIM;
  const unsigned short* vbase = Vtb + (size_t)bh * HDIM * SEQ_T;
  const int sr = tid >> 3;             // staging row 0..31
  const int lc = tid & 7;              // dest 16B chunk slot
  const int sw8 = (lc ^ (sr & 7)) * 8; // pre-swizzled SOURCE chunk offset

  // stage K/V tile kt into parity slot p of buffer b (4 DMAs / thread)
  auto stage1 = [&](int b, int p, int kt) {
    const unsigned short* kp = kbase + (size_t)(kt * 64 + sr) * 64 + sw8;
    async_lds16(kp, &Kp[b][p][tid * 8]);
    async_lds16(kp + 32 * 64, &Kp[b][p][2048 + tid * 8]);
    const unsigned short* vp = vbase + (size_t)sr * SEQ_T + kt * 64 + sw8;
    async_lds16(vp, &Vp[b][p][tid * 8]);
    async_lds16(vp + (size_t)32 * SEQ_T, &Vp[b][p][2048 + tid * 8]);
  };

  const f32x16 Z16 = {0.f, 0.f, 0.f, 0.f, 0.f, 0.f, 0.f, 0.f,
                      0.f, 0.f, 0.f, 0.f, 0.f, 0.f, 0.f, 0.f};
  f32x16 O0 = Z16, O1 = Z16;
  float l_acc = 0.f;
  bf16x8 qf[4];

  // tile compute: QK^T (8 MFMA) -> exp2/pack -> permlane swaps -> PV (8 MFMA)
  auto tile_compute = [&](const unsigned short* Ksrc,
                          const unsigned short* Vsrc, int lim, bool masked) {
    f32x16 S0 = Z16, S1 = Z16;
    __builtin_amdgcn_s_setprio(1);
#pragma unroll
    for (int cc = 0; cc < 4; ++cc) {
      const int slot = ((cc << 1) | h) ^ r7l;
      const bf16x8 k0 = *(const bf16x8*)&Ksrc[l31 * 64 + slot * 8];
      const bf16x8 k1 = *(const bf16x8*)&Ksrc[(32 + l31) * 64 + slot * 8];
      S0 = __builtin_amdgcn_mfma_f32_32x32x16_bf16(k0, qf[cc], S0, 0, 0, 0);
      S1 = __builtin_amdgcn_mfma_f32_32x32x16_bf16(k1, qf[cc], S1, 0, 0, 0);
    }
    __builtin_amdgcn_s_setprio(0);
    // lane holds S[key = kl][q = l31]; kl = (r&3)+8*(r>>2)+4h (S0), +32 (S1).
    unsigned int pk0[8], pk1[8];
#pragma unroll
    for (int m = 0; m < 8; ++m) {
      float p0 = __builtin_amdgcn_exp2f(S0[2 * m] - SSHIFT);
      float p1 = __builtin_amdgcn_exp2f(S0[2 * m + 1] - SSHIFT);
      float p2 = __builtin_amdgcn_exp2f(S1[2 * m] - SSHIFT);
      float p3 = __builtin_amdgcn_exp2f(S1[2 * m + 1] - SSHIFT);
      if (masked) {
        const int r0 = 2 * m, r1 = 2 * m + 1;
        const int kl0 = (r0 & 3) + 8 * (r0 >> 2) + 4 * h;
        const int kl1 = (r1 & 3) + 8 * (r1 >> 2) + 4 * h;
        p0 = (kl0 > lim) ? 0.f : p0;
        p1 = (kl1 > lim) ? 0.f : p1;
        p2 = (kl0 + 32 > lim) ? 0.f : p2;
        p3 = (kl1 + 32 > lim) ? 0.f : p3;
      }
      l_acc += (p0 + p1) + (p2 + p3);
      pk0[m] = pack_bf16(p0, p1);
      pk1[m] = pack_bf16(p2, p3);
    }
    // redistribute: for chunk pair tp: swap(pk[4tp+i], pk[4tp+2+i]) i=0,1
#pragma unroll
    for (int tp = 0; tp < 2; ++tp) {
      plswap(pk0[4 * tp + 0], pk0[4 * tp + 2]);
      plswap(pk0[4 * tp + 1], pk0[4 * tp + 3]);
      plswap(pk1[4 * tp + 0], pk1[4 * tp + 2]);
      plswap(pk1[4 * tp + 1], pk1[4 * tp + 3]);
    }
    // PV: chunk t = 2*kb + tp covers keys 16t..16t+15
#pragma unroll
    for (int kb = 0; kb < 2; ++kb)
#pragma unroll
      for (int tp = 0; tp < 2; ++tp) {
        const int t = 2 * kb + tp;
        uint4 wv;
        if (kb == 0)
          wv = (uint4){pk0[4 * tp + 0], pk0[4 * tp + 1], pk0[4 * tp + 2],
                       pk0[4 * tp + 3]};
        else
          wv = (uint4){pk1[4 * tp + 0], pk1[4 * tp + 1], pk1[4 * tp + 2],
                       pk1[4 * tp + 3]};
        const bf16x8 pb = *(const bf16x8*)&wv;
        const int slot = ((t << 1) | h) ^ r7l;
        const bf16x8 v0 = *(const bf16x8*)&Vsrc[l31 * 64 + slot * 8];
        const bf16x8 v1 = *(const bf16x8*)&Vsrc[(32 + l31) * 64 + slot * 8];
        __builtin_amdgcn_s_setprio(1);
        O0 = __builtin_amdgcn_mfma_f32_32x32x16_bf16(v0, pb, O0, 0, 0, 0);
        O1 = __builtin_amdgcn_mfma_f32_32x32x16_bf16(v1, pb, O1, 0, 0, 0);
        __builtin_amdgcn_s_setprio(0);
      }
  };

  for (int ph = 0; ph < 2; ++ph) {
    const int qt = ph ? (31 - pr) : pr;       // 64-query tile index, 0..31
    const int qglob = qt * 64 + qhalf * 32 + l31;

    // Q B-fragments: qf[c] = Q[d = c*16 + h*8 + j][q = qglob]
    {
      unsigned short qraw[32];
      const unsigned short* qp =
          Qtb + ((size_t)bh * HDIM + h * 8) * SEQ_T + qglob;
#pragma unroll
      for (int cc = 0; cc < 4; ++cc)
#pragma unroll
        for (int jj = 0; jj < 8; ++jj)
          qraw[cc * 8 + jj] = qp[(size_t)(cc * 16 + jj) * SEQ_T];
#pragma unroll
      for (int cc = 0; cc < 4; ++cc) qf[cc] = *(const bf16x8*)(qraw + cc * 8);
    }
    O0 = Z16;
    O1 = Z16;
    l_acc = 0.f;

    const int S = (qt + 2) >> 1;  // ceil((qt+1)/2) pair-steps
    // prologue: stage pair (0,1) into buffer 0 (clamped to valid range)
    stage1(0, 0, 0);
    stage1(0, 1, qt < 1 ? qt : 1);
    __syncthreads();

    for (int s = 0; s < S; ++s) {
      const int cur = s & 1;
      if (s + 1 < S) {
        const int ka = 2 * s + 2, kb2 = 2 * s + 3;
        stage1(cur ^ 1, 0, ka > qt ? qt : ka);
        stage1(cur ^ 1, 1, kb2 > qt ? qt : kb2);
      }
      const int kt = 2 * s + ks;  // this wave's key-tile
      if (kt <= qt) {
        if (kt == qt)
          tile_compute(&Kp[cur][ks][0], &Vp[cur][ks][0], qhalf * 32 + l31,
                       true);
        else
          tile_compute(&Kp[cur][ks][0], &Vp[cur][ks][0], 0, false);
      }
      __syncthreads();  // also drains staging DMAs (vmcnt) for next step
    }

    // ---- combine parity partials (fixed shift => plain adds) ----
    l_acc += __shfl_xor(l_acc, 32, 64);  // full parity-l for q = l31
    float* osc = (float*)&Kp[0][0][0];   // [2 qhalf][32 reg][64 lane] = 16KB
    float* lsc = (float*)&Vp[0][0][0];   // [2 qhalf][64 lane]
    if (ks == 1) {
#pragma unroll
      for (int r = 0; r < 16; ++r) {
        osc[(qhalf * 32 + r) * 64 + lane] = O0[r];
        osc[(qhalf * 32 + 16 + r) * 64 + lane] = O1[r];
      }
      lsc[qhalf * 64 + lane] = l_acc;
    }
    __syncthreads();
    if (ks == 0) {
      l_acc += lsc[qhalf * 64 + lane];
      const float inv = 1.0f / fmaxf(l_acc, 1e-30f);
#pragma unroll
      for (int r = 0; r < 16; ++r) {
        O0[r] += osc[(qhalf * 32 + r) * 64 + lane];
        O1[r] += osc[(qhalf * 32 + 16 + r) * 64 + lane];
      }
      const int bb = bh >> 3, hh = bh & 7;
      unsigned short* dst =
          AOb + ((size_t)bb * SEQ_T + qglob) * D_MODEL + (hh << 6);
#pragma unroll
      for (int rg = 0; rg < 4; ++rg) {
        ushort4 o0 = {f2bf(O0[4 * rg + 0] * inv), f2bf(O0[4 * rg + 1] * inv),
                      f2bf(O0[4 * rg + 2] * inv), f2bf(O0[4 * rg + 3] * inv)};
        *(ushort4*)(dst + 8 * rg + 4 * h) = o0;
        ushort4 o1 = {f2bf(O1[4 * rg + 0] * inv), f2bf(O1[4 * rg + 1] * inv),
                      f2bf(O1[4 * rg + 2] * inv), f2bf(O1[4 * rg + 3] * inv)};
        *(ushort4*)(dst + 32 + 8 * rg + 4 * h) = o1;
      }
    }
    __syncthreads();  // scratch dead before next phase re-stages over it
  }
}

// ---------------------------------------------------------------------------
// Kernel 3: output projection, bf16 MFMA. 64x128 tile (512 blocks, 2/CU),
// BK=64 swizzled. AOb[8192][512] @ Wot[512][512]^T + b -> fp32 out.
// ---------------------------------------------------------------------------
__global__ __launch_bounds__(256) void gemm_out_mfma(
    const unsigned short* __restrict__ AOb, const unsigned short* __restrict__ Wot,
    const float* __restrict__ bias, float* __restrict__ out) {
  __shared__ unsigned short As[64 * 64];
  __shared__ unsigned short Bs[128 * 64];
  const int tid = threadIdx.x;
  const int w = tid >> 6, lane = tid & 63;
  const int quad = lane >> 4, l15 = lane & 15;
  const int m0 = blockIdx.x * 64, n0 = blockIdx.y * 128;

  const int srow = tid >> 3;
  const int schunk = (tid & 7) ^ (srow & 7);
  const unsigned short* ga = AOb + (size_t)(m0 + srow) * 512 + schunk * 8;
  const unsigned short* gb = Wot + (size_t)(n0 + srow) * 512 + schunk * 8;
  unsigned short* lA = As + tid * 8;
  unsigned short* lB = Bs + tid * 8;

  f32x4 acc[4][2] = {};
  for (int k0 = 0; k0 < 512; k0 += 64) {
#pragma unroll
    for (int rr = 0; rr < 2; ++rr)
      async_lds16(ga + (size_t)rr * 32 * 512 + k0, lA + rr * 2048);
#pragma unroll
    for (int rr = 0; rr < 4; ++rr)
      async_lds16(gb + (size_t)rr * 32 * 512 + k0, lB + rr * 2048);
    __syncthreads();
    bf16x8 af[4][2], bfr[2][2];
#pragma unroll
    for (int mb = 0; mb < 4; ++mb) {
      int row = mb * 16 + l15;
#pragma unroll
      for (int kk = 0; kk < 2; ++kk) {
        int slot = (kk * 4 + quad) ^ (row & 7);
        af[mb][kk] = *(const bf16x8*)&As[row * 64 + slot * 8];
      }
    }
#pragma unroll
    for (int nb = 0; nb < 2; ++nb) {
      int row = w * 32 + nb * 16 + l15;
#pragma unroll
      for (int kk = 0; kk < 2; ++kk) {
        int slot = (kk * 4 + quad) ^ (row & 7);
        bfr[nb][kk] = *(const bf16x8*)&Bs[row * 64 + slot * 8];
      }
    }
#pragma unroll
    for (int mb = 0; mb < 4; ++mb)
#pragma unroll
      for (int nb = 0; nb < 2; ++nb) {
        acc[mb][nb] = __builtin_amdgcn_mfma_f32_16x16x32_bf16(
            af[mb][0], bfr[nb][0], acc[mb][nb], 0, 0, 0);
        acc[mb][nb] = __builtin_amdgcn_mfma_f32_16x16x32_bf16(
            af[mb][1], bfr[nb][1], acc[mb][nb], 0, 0, 0);
      }
    __syncthreads();
  }

  const int cbase = n0 + w * 32;
  float bv[2];
#pragma unroll
  for (int nb = 0; nb < 2; ++nb) bv[nb] = bias[cbase + nb * 16 + l15];
#pragma unroll
  for (int mb = 0; mb < 4; ++mb)
#pragma unroll
    for (int nb = 0; nb < 2; ++nb)
#pragma unroll
      for (int r = 0; r < 4; ++r)
        out[(size_t)(m0 + mb * 16 + quad * 4 + r) * 512 + cbase + nb * 16 +
            l15] = acc[mb][nb][r] + bv[nb];
}

// ---------------------------------------------------------------------------
extern "C" void kernel_launch(void* const* d_in, const int* in_sizes, int n_in,
                              void* d_out, int out_size, void* d_ws,
                              size_t ws_size, hipStream_t stream) {
  const float* x     = (const float*)d_in[0];
  const float* W_qkv = (const float*)d_in[1];
  const float* b_qkv = (const float*)d_in[2];
  const float* W_out = (const float*)d_in[3];
  const float* b_out = (const float*)d_in[4];
  float* out = (float*)d_out;

  const size_t NX = (size_t)4 * SEQ_T * D_MODEL;        // 4,194,304
  unsigned short* xb   = (unsigned short*)d_ws;          // [8192][512]
  unsigned short* Wqkt = xb + NX;                        // [1536][512]
  unsigned short* Wot  = Wqkt + (size_t)1536 * 512;      // [512][512]
  unsigned short* Qtb  = Wot + (size_t)512 * 512;        // [bh][d][t]
  unsigned short* Kb   = Qtb + NX;                       // [bh][t][d]
  unsigned short* Vtb  = Kb + NX;                        // [bh][dv][t]
  unsigned short* AOb  = Vtb + NX;                       // [8192][512]

  prep_kernel<<<2304, 256, 0, stream>>>(x, W_qkv, W_out, xb, Wqkt, Wot);
  gemm_qkv_mfma<<<dim3(64, 12), 256, 0, stream>>>(xb, Wqkt, b_qkv, Qtb, Kb,
                                                  Vtb);
  attn_mfma8<<<dim3(512), 256, 0, stream>>>(Qtb, Kb, Vtb, AOb);
  gemm_out_mfma<<<dim3(128, 4), 256, 0, stream>>>(AOb, Wot, b_out, out);
}

// Round 7
// 134.857 us; speedup vs baseline: 1.0957x; 1.0219x over previous
//
#include <hip/hip_runtime.h>
#include <cstdint>
#include <cstddef>

#define D_MODEL 512
#define SEQ_T 2048
#define NHEADS 8
#define HDIM 64

typedef __attribute__((ext_vector_type(8))) short bf16x8;
typedef __attribute__((ext_vector_type(4))) float f32x4;

__device__ __forceinline__ unsigned short f2bf(float f) {
  unsigned int u = __float_as_uint(f);
  u += 0x7FFFu + ((u >> 16) & 1u);
  return (unsigned short)(u >> 16);
}

// pack two f32 -> two bf16 in one uint (round via +0x8000, v_perm)
__device__ __forceinline__ unsigned int pack_bf16(float lo, float hi) {
  unsigned int a = __float_as_uint(lo) + 0x8000u;
  unsigned int b = __float_as_uint(hi) + 0x8000u;
  return __builtin_amdgcn_perm(b, a, 0x07060302u);
}

// Q pre-scaled by 1/sqrt(64) * log2(e) so softmax runs in exp2 domain.
#define QSCALE 0.18033688011112043f
// fixed softmax shift: p = exp2(s - SSHIFT); common factor cancels in O/l.
#define SSHIFT 16.0f

// async global->LDS, 16B per lane. LDS dest = wave-uniform base + lane*16.
__device__ __forceinline__ void async_lds16(const unsigned short* g,
                                            unsigned short* l) {
  __builtin_amdgcn_global_load_lds(
      (const __attribute__((address_space(1))) void*)g,
      (__attribute__((address_space(3))) void*)l, 16, 0, 0);
}

// ---------------------------------------------------------------------------
// Fused prep: [0,2048) cast x -> bf16; [2048,2240) transpose W_qkv;
// [2240,2304) transpose W_out.
// ---------------------------------------------------------------------------
__global__ __launch_bounds__(256) void prep_kernel(
    const float* __restrict__ x, const float* __restrict__ W_qkv,
    const float* __restrict__ W_out, unsigned short* __restrict__ xb,
    unsigned short* __restrict__ Wqkt, unsigned short* __restrict__ Wot) {
  __shared__ float tile[64][65];
  const int bid = blockIdx.x;
  if (bid < 2048) {
    int i = (bid * 256 + threadIdx.x) * 8;
    float4 a = *(const float4*)(x + i);
    float4 b = *(const float4*)(x + i + 4);
    ushort4 lo = {f2bf(a.x), f2bf(a.y), f2bf(a.z), f2bf(a.w)};
    ushort4 hi = {f2bf(b.x), f2bf(b.y), f2bf(b.z), f2bf(b.w)};
    *(ushort4*)(xb + i) = lo;
    *(ushort4*)(xb + i + 4) = hi;
    return;
  }
  const float* src;
  unsigned short* dst;
  int R = 512, C, c0, r0;
  if (bid < 2048 + 192) {
    int t = bid - 2048;
    C = 1536; c0 = (t % 24) * 64; r0 = (t / 24) * 64;
    src = W_qkv; dst = Wqkt;
  } else {
    int t = bid - 2240;
    C = 512; c0 = (t & 7) * 64; r0 = (t >> 3) * 64;
    src = W_out; dst = Wot;
  }
  for (int i = threadIdx.x; i < 64 * 64; i += 256) {
    int r = i >> 6, c = i & 63;
    tile[r][c] = src[(size_t)(r0 + r) * C + c0 + c];
  }
  __syncthreads();
  for (int i = threadIdx.x; i < 64 * 64; i += 256) {
    int c = i >> 6, r = i & 63;
    dst[(size_t)(c0 + c) * R + r0 + r] = f2bf(tile[r][c]);
  }
}

// ---------------------------------------------------------------------------
// Kernel 1: QKV projection, bf16 MFMA. 128x128 tile, BK=64 (8 K-iters),
// XOR-swizzled LDS (16B chunk ^= row&7) -> conflict-free b128 fragment reads.
// Epilogue: Q -> bf16 [bh][d][t] TRANSPOSED packed ushort4 (pre-scaled);
// V -> bf16 [bh][dv][t] packed ushort4; K -> bf16 [bh][t][d] scalar.
// ---------------------------------------------------------------------------
__global__ __launch_bounds__(256) void gemm_qkv_mfma(
    const unsigned short* __restrict__ xb, const unsigned short* __restrict__ Wt,
    const float* __restrict__ bias, unsigned short* __restrict__ Qtb,
    unsigned short* __restrict__ Kb, unsigned short* __restrict__ Vtb) {
  __shared__ unsigned short As[128 * 64];
  __shared__ unsigned short Bs[128 * 64];
  const int tid = threadIdx.x;
  const int w = tid >> 6, lane = tid & 63;
  const int quad = lane >> 4, l15 = lane & 15;
  const int wm = w >> 1, wn = w & 1;
  const int m0 = blockIdx.x * 128, n0 = blockIdx.y * 128;

  const int srow = tid >> 3;                   // 0..31
  const int schunk = (tid & 7) ^ (srow & 7);   // logical chunk loaded
  const unsigned short* ga = xb + (size_t)(m0 + srow) * 512 + schunk * 8;
  const unsigned short* gb = Wt + (size_t)(n0 + srow) * 512 + schunk * 8;
  unsigned short* lA = As + tid * 8;
  unsigned short* lB = Bs + tid * 8;

  f32x4 acc[4][4] = {};
  for (int k0 = 0; k0 < 512; k0 += 64) {
#pragma unroll
    for (int rr = 0; rr < 4; ++rr) {
      async_lds16(ga + (size_t)rr * 32 * 512 + k0, lA + rr * 2048);
      async_lds16(gb + (size_t)rr * 32 * 512 + k0, lB + rr * 2048);
    }
    __syncthreads();
    bf16x8 af[4][2], bfr[4][2];
#pragma unroll
    for (int mb = 0; mb < 4; ++mb) {
      int row = wm * 64 + mb * 16 + l15;
#pragma unroll
      for (int kk = 0; kk < 2; ++kk) {
        int slot = (kk * 4 + quad) ^ (row & 7);
        af[mb][kk] = *(const bf16x8*)&As[row * 64 + slot * 8];
      }
    }
#pragma unroll
    for (int nb = 0; nb < 4; ++nb) {
      int row = wn * 64 + nb * 16 + l15;
#pragma unroll
      for (int kk = 0; kk < 2; ++kk) {
        int slot = (kk * 4 + quad) ^ (row & 7);
        bfr[nb][kk] = *(const bf16x8*)&Bs[row * 64 + slot * 8];
      }
    }
#pragma unroll
    for (int mb = 0; mb < 4; ++mb)
#pragma unroll
      for (int nb = 0; nb < 4; ++nb) {
        acc[mb][nb] = __builtin_amdgcn_mfma_f32_16x16x32_bf16(
            af[mb][0], bfr[nb][0], acc[mb][nb], 0, 0, 0);
        acc[mb][nb] = __builtin_amdgcn_mfma_f32_16x16x32_bf16(
            af[mb][1], bfr[nb][1], acc[mb][nb], 0, 0, 0);
      }
    __syncthreads();
  }

  const int cbase = n0 + wn * 64;
  const int three = cbase >> 9;          // 0:Q 1:K 2:V
  const int h = (cbase >> 6) & 7;
  const int bh = ((m0 >> 11) << 3) + h;
  const int t0 = (m0 & 2047) + wm * 64;
  float bv[4];
#pragma unroll
  for (int nb = 0; nb < 4; ++nb) bv[nb] = bias[cbase + nb * 16 + l15];

  if (three == 0) {
    // Q transposed [bh][d][t], pre-scaled, packed along t
#pragma unroll
    for (int mb = 0; mb < 4; ++mb)
#pragma unroll
      for (int nb = 0; nb < 4; ++nb) {
        int trow = t0 + mb * 16 + quad * 4;
        ushort4 v = {f2bf((acc[mb][nb][0] + bv[nb]) * QSCALE),
                     f2bf((acc[mb][nb][1] + bv[nb]) * QSCALE),
                     f2bf((acc[mb][nb][2] + bv[nb]) * QSCALE),
                     f2bf((acc[mb][nb][3] + bv[nb]) * QSCALE)};
        *(ushort4*)(Qtb + ((size_t)bh * HDIM + nb * 16 + l15) * SEQ_T + trow) = v;
      }
  } else if (three == 2) {
    // V transposed [bh][dv][t], packed along t
#pragma unroll
    for (int mb = 0; mb < 4; ++mb)
#pragma unroll
      for (int nb = 0; nb < 4; ++nb) {
        int trow = t0 + mb * 16 + quad * 4;
        ushort4 v = {f2bf(acc[mb][nb][0] + bv[nb]), f2bf(acc[mb][nb][1] + bv[nb]),
                     f2bf(acc[mb][nb][2] + bv[nb]), f2bf(acc[mb][nb][3] + bv[nb])};
        *(ushort4*)(Vtb + ((size_t)bh * HDIM + nb * 16 + l15) * SEQ_T + trow) = v;
      }
  } else {
    // K row-major [bh][t][d] (required for attn A-fragment contiguity)
#pragma unroll
    for (int mb = 0; mb < 4; ++mb)
#pragma unroll
      for (int nb = 0; nb < 4; ++nb)
#pragma unroll
        for (int r = 0; r < 4; ++r) {
          int trow = t0 + mb * 16 + quad * 4 + r;
          Kb[((size_t)bh * SEQ_T + trow) * HDIM + nb * 16 + l15] =
              f2bf(acc[mb][nb][r] + bv[nb]);
        }
  }
}

// ---------------------------------------------------------------------------
// Kernel 2 (v5 + T5): causal flash attention, 16x16x32 MFMAs.
//  - balanced grid: each CU-slot's 4 blocks get qt {31-k,16+k,15-k,k} -> 66
//    tiles per CU exactly; longest-first dispatch order; 4 blocks/CU
//    (40 KB LDS, launch_bounds(256,4)) -> 16 waves/CU TLP
//  - peeled diagonal tile -> branch-free main loop
//  - l accumulated via 2 extra MFMAs (A = ones): no VALU adds, no shuffles
//  - double-buffered swizzled LDS staging, 1 barrier/tile
//  - fixed-shift softmax p = exp2(s-16)
//  - v9: s_setprio(1) around MFMA clusters (T5; m191 regime: 4 independent
//    co-resident blocks at different phases per CU)
// ---------------------------------------------------------------------------
__global__ __launch_bounds__(256, 4) void attn_mfma5(
    const unsigned short* __restrict__ Qtb, const unsigned short* __restrict__ Kb,
    const unsigned short* __restrict__ Vtb, unsigned short* __restrict__ AOb) {
  __shared__ __align__(16) unsigned short Ks[2][64 * 64];
  __shared__ __align__(16) unsigned short Vs[2][64 * 64];
  __shared__ __align__(16) unsigned short Pt[4][16 * 64];
  const int tid = threadIdx.x;
  const int w = tid >> 6, lane = tid & 63;
  const int quad = lane >> 4, l15 = lane & 15;

  // balanced (bh, qt) mapping
  const int bid = blockIdx.x;
  const int xcd = bid & 7;
  const int j = bid >> 3;            // 0..127
  const int c = j & 31, g = j >> 5;  // CU slot within XCD, co-res slot
  const int k = c >> 2;
  const int bh = xcd + 8 * (c & 3);
  const int qt = (g == 0) ? (31 - k) : (g == 1) ? (16 + k)
               : (g == 2) ? (15 - k) : k;

  const unsigned short* kbase = Kb + (size_t)bh * SEQ_T * HDIM;
  const unsigned short* vbase = Vtb + (size_t)bh * HDIM * SEQ_T;
  const int sr = tid >> 3;             // staging row 0..31
  const int lc = tid & 7;              // logical 16B chunk
  const int scol = lc * 8;
  const int swc = (lc ^ (sr & 7)) * 8; // swizzled slot offset

  // Q B-fragments from transposed Qtb[bh][d][t]: 16 scalar loads, once.
  bf16x8 qf0, qf1;
  {
    unsigned short qraw[16];
    const unsigned short* qp =
        Qtb + ((size_t)bh * HDIM + quad * 8) * SEQ_T + qt * 64 + w * 16 + l15;
#pragma unroll
    for (int jj = 0; jj < 8; ++jj) {
      qraw[jj] = qp[(size_t)jj * SEQ_T];
      qraw[8 + jj] = qp[(size_t)(32 + jj) * SEQ_T];
    }
    qf0 = *(const bf16x8*)qraw;
    qf1 = *(const bf16x8*)(qraw + 8);
  }
  const short oneb = (short)0x3F80;
  const bf16x8 ones = {oneb, oneb, oneb, oneb, oneb, oneb, oneb, oneb};

  f32x4 O[4] = {{0.f, 0.f, 0.f, 0.f}, {0.f, 0.f, 0.f, 0.f},
                {0.f, 0.f, 0.f, 0.f}, {0.f, 0.f, 0.f, 0.f}};
  f32x4 l_acc = {0.f, 0.f, 0.f, 0.f};
  const int q_rel = w * 16 + l15;
  const int r7 = l15 & 7;

  // stage tile 0 into buffer 0
  uint4 rk0, rk1, rv0, rv1;
  {
    const unsigned short* kp = kbase + (size_t)sr * 64 + scol;
    rk0 = *(const uint4*)kp;
    rk1 = *(const uint4*)(kp + 32 * 64);
    const unsigned short* vp = vbase + (size_t)sr * SEQ_T + scol;
    rv0 = *(const uint4*)vp;
    rv1 = *(const uint4*)(vp + 32 * SEQ_T);
  }
  *(uint4*)&Ks[0][sr * 64 + swc] = rk0;
  *(uint4*)&Ks[0][(sr + 32) * 64 + swc] = rk1;
  *(uint4*)&Vs[0][sr * 64 + swc] = rv0;
  *(uint4*)&Vs[0][(sr + 32) * 64 + swc] = rv1;
  __syncthreads();

  // ---- main loop: off-diagonal tiles, branch-free ----
  for (int i = 0; i < qt; ++i) {
    const int cur = i & 1;
    // prefetch tile i+1 (i+1 <= qt always valid)
    {
      const int nkt = i + 1;
      const unsigned short* kp = kbase + (size_t)(nkt * 64 + sr) * 64 + scol;
      rk0 = *(const uint4*)kp;
      rk1 = *(const uint4*)(kp + 32 * 64);
      const unsigned short* vp = vbase + (size_t)sr * SEQ_T + nkt * 64 + scol;
      rv0 = *(const uint4*)vp;
      rv1 = *(const uint4*)(vp + 32 * SEQ_T);
    }

    f32x4 S[4];
    __builtin_amdgcn_s_setprio(1);
#pragma unroll
    for (int nb = 0; nb < 4; ++nb) {
      const int row = nb * 16 + l15;
      const unsigned short* k0p = &Ks[cur][row * 64 + ((quad ^ r7) * 8)];
      const unsigned short* k1p = &Ks[cur][row * 64 + (((quad + 4) ^ r7) * 8)];
      f32x4 z = {0.f, 0.f, 0.f, 0.f};
      z = __builtin_amdgcn_mfma_f32_16x16x32_bf16(*(const bf16x8*)k0p, qf0, z,
                                                  0, 0, 0);
      S[nb] = __builtin_amdgcn_mfma_f32_16x16x32_bf16(*(const bf16x8*)k1p, qf1,
                                                      z, 0, 0, 0);
    }
    __builtin_amdgcn_s_setprio(0);

#pragma unroll
    for (int nb = 0; nb < 4; ++nb) {
      float p0 = __builtin_amdgcn_exp2f(S[nb][0] - SSHIFT);
      float p1 = __builtin_amdgcn_exp2f(S[nb][1] - SSHIFT);
      float p2 = __builtin_amdgcn_exp2f(S[nb][2] - SSHIFT);
      float p3 = __builtin_amdgcn_exp2f(S[nb][3] - SSHIFT);
      int cc = 2 * nb + (quad >> 1);
      uint2 pk = {pack_bf16(p0, p1), pack_bf16(p2, p3)};
      *(uint2*)&Pt[w][l15 * 64 + ((cc ^ r7) * 8) + (quad & 1) * 4] = pk;
    }

    bf16x8 pb0 = *(const bf16x8*)&Pt[w][l15 * 64 + ((quad ^ r7) * 8)];
    bf16x8 pb1 = *(const bf16x8*)&Pt[w][l15 * 64 + (((quad + 4) ^ r7) * 8)];
    __builtin_amdgcn_s_setprio(1);
    l_acc = __builtin_amdgcn_mfma_f32_16x16x32_bf16(ones, pb0, l_acc, 0, 0, 0);
    l_acc = __builtin_amdgcn_mfma_f32_16x16x32_bf16(ones, pb1, l_acc, 0, 0, 0);
#pragma unroll
    for (int nbd = 0; nbd < 4; ++nbd) {
      const int row = nbd * 16 + l15;
      const unsigned short* v0p = &Vs[cur][row * 64 + ((quad ^ r7) * 8)];
      const unsigned short* v1p = &Vs[cur][row * 64 + (((quad + 4) ^ r7) * 8)];
      O[nbd] = __builtin_amdgcn_mfma_f32_16x16x32_bf16(*(const bf16x8*)v0p, pb0,
                                                       O[nbd], 0, 0, 0);
      O[nbd] = __builtin_amdgcn_mfma_f32_16x16x32_bf16(*(const bf16x8*)v1p, pb1,
                                                       O[nbd], 0, 0, 0);
    }
    __builtin_amdgcn_s_setprio(0);

    const int nxt = cur ^ 1;
    *(uint4*)&Ks[nxt][sr * 64 + swc] = rk0;
    *(uint4*)&Ks[nxt][(sr + 32) * 64 + swc] = rk1;
    *(uint4*)&Vs[nxt][sr * 64 + swc] = rv0;
    *(uint4*)&Vs[nxt][(sr + 32) * 64 + swc] = rv1;
    __syncthreads();
  }

  // ---- diagonal tile ----
  {
    const int cur = qt & 1;
    const int nb_lim = w + 1;
    f32x4 S[4];
    __builtin_amdgcn_s_setprio(1);
#pragma unroll
    for (int nb = 0; nb < 4; ++nb) {
      if (nb < nb_lim) {
        const int row = nb * 16 + l15;
        const unsigned short* k0p = &Ks[cur][row * 64 + ((quad ^ r7) * 8)];
        const unsigned short* k1p =
            &Ks[cur][row * 64 + (((quad + 4) ^ r7) * 8)];
        f32x4 z = {0.f, 0.f, 0.f, 0.f};
        z = __builtin_amdgcn_mfma_f32_16x16x32_bf16(*(const bf16x8*)k0p, qf0,
                                                    z, 0, 0, 0);
        S[nb] = __builtin_amdgcn_mfma_f32_16x16x32_bf16(*(const bf16x8*)k1p,
                                                        qf1, z, 0, 0, 0);
      }
    }
    __builtin_amdgcn_s_setprio(0);
#pragma unroll
    for (int nb = 0; nb < 4; ++nb) {
      int cc = 2 * nb + (quad >> 1);
      if (nb < nb_lim) {
        float pp[4];
#pragma unroll
        for (int r = 0; r < 4; ++r) {
          float p = __builtin_amdgcn_exp2f(S[nb][r] - SSHIFT);
          int key_rel = nb * 16 + quad * 4 + r;
          pp[r] = (key_rel > q_rel) ? 0.f : p;
        }
        uint2 pk = {pack_bf16(pp[0], pp[1]), pack_bf16(pp[2], pp[3])};
        *(uint2*)&Pt[w][l15 * 64 + ((cc ^ r7) * 8) + (quad & 1) * 4] = pk;
      } else {
        uint2 z2 = {0u, 0u};
        *(uint2*)&Pt[w][l15 * 64 + ((cc ^ r7) * 8) + (quad & 1) * 4] = z2;
      }
    }
    const int kpv = (w >= 2) ? 2 : 1;
    bf16x8 pb0 = *(const bf16x8*)&Pt[w][l15 * 64 + ((quad ^ r7) * 8)];
    bf16x8 pb1 = *(const bf16x8*)&Pt[w][l15 * 64 + (((quad + 4) ^ r7) * 8)];
    __builtin_amdgcn_s_setprio(1);
    l_acc = __builtin_amdgcn_mfma_f32_16x16x32_bf16(ones, pb0, l_acc, 0, 0, 0);
    if (kpv == 2)
      l_acc =
          __builtin_amdgcn_mfma_f32_16x16x32_bf16(ones, pb1, l_acc, 0, 0, 0);
#pragma unroll
    for (int nbd = 0; nbd < 4; ++nbd) {
      const int row = nbd * 16 + l15;
      const unsigned short* v0p = &Vs[cur][row * 64 + ((quad ^ r7) * 8)];
      O[nbd] = __builtin_amdgcn_mfma_f32_16x16x32_bf16(*(const bf16x8*)v0p, pb0,
                                                       O[nbd], 0, 0, 0);
      if (kpv == 2) {
        const unsigned short* v1p =
            &Vs[cur][row * 64 + (((quad + 4) ^ r7) * 8)];
        O[nbd] = __builtin_amdgcn_mfma_f32_16x16x32_bf16(*(const bf16x8*)v1p,
                                                         pb1, O[nbd], 0, 0, 0);
      }
    }
    __builtin_amdgcn_s_setprio(0);
  }

  // l is identical across the 4 C-rows per lane: no reduction needed.
  float inv = 1.0f / l_acc[0];
  const int bb = bh >> 3, h = bh & 7;
  int qrow = qt * 64 + q_rel;
  unsigned short* dst = AOb + ((size_t)bb * SEQ_T + qrow) * D_MODEL + (h << 6);
#pragma unroll
  for (int nbd = 0; nbd < 4; ++nbd) {
    ushort4 o4 = {f2bf(O[nbd][0] * inv), f2bf(O[nbd][1] * inv),
                  f2bf(O[nbd][2] * inv), f2bf(O[nbd][3] * inv)};
    *(ushort4*)(dst + nbd * 16 + quad * 4) = o4;
  }
}

// ---------------------------------------------------------------------------
// Kernel 3: output projection, bf16 MFMA. 64x128 tile (512 blocks, 2/CU),
// BK=64 swizzled. AOb[8192][512] @ Wot[512][512]^T + b -> fp32 out.
// ---------------------------------------------------------------------------
__global__ __launch_bounds__(256) void gemm_out_mfma(
    const unsigned short* __restrict__ AOb, const unsigned short* __restrict__ Wot,
    const float* __restrict__ bias, float* __restrict__ out) {
  __shared__ unsigned short As[64 * 64];
  __shared__ unsigned short Bs[128 * 64];
  const int tid = threadIdx.x;
  const int w = tid >> 6, lane = tid & 63;
  const int quad = lane >> 4, l15 = lane & 15;
  const int m0 = blockIdx.x * 64, n0 = blockIdx.y * 128;

  const int srow = tid >> 3;
  const int schunk = (tid & 7) ^ (srow & 7);
  const unsigned short* ga = AOb + (size_t)(m0 + srow) * 512 + schunk * 8;
  const unsigned short* gb = Wot + (size_t)(n0 + srow) * 512 + schunk * 8;
  unsigned short* lA = As + tid * 8;
  unsigned short* lB = Bs + tid * 8;

  f32x4 acc[4][2] = {};
  for (int k0 = 0; k0 < 512; k0 += 64) {
#pragma unroll
    for (int rr = 0; rr < 2; ++rr)
      async_lds16(ga + (size_t)rr * 32 * 512 + k0, lA + rr * 2048);
#pragma unroll
    for (int rr = 0; rr < 4; ++rr)
      async_lds16(gb + (size_t)rr * 32 * 512 + k0, lB + rr * 2048);
    __syncthreads();
    bf16x8 af[4][2], bfr[2][2];
#pragma unroll
    for (int mb = 0; mb < 4; ++mb) {
      int row = mb * 16 + l15;
#pragma unroll
      for (int kk = 0; kk < 2; ++kk) {
        int slot = (kk * 4 + quad) ^ (row & 7);
        af[mb][kk] = *(const bf16x8*)&As[row * 64 + slot * 8];
      }
    }
#pragma unroll
    for (int nb = 0; nb < 2; ++nb) {
      int row = w * 32 + nb * 16 + l15;
#pragma unroll
      for (int kk = 0; kk < 2; ++kk) {
        int slot = (kk * 4 + quad) ^ (row & 7);
        bfr[nb][kk] = *(const bf16x8*)&Bs[row * 64 + slot * 8];
      }
    }
#pragma unroll
    for (int mb = 0; mb < 4; ++mb)
#pragma unroll
      for (int nb = 0; nb < 2; ++nb) {
        acc[mb][nb] = __builtin_amdgcn_mfma_f32_16x16x32_bf16(
            af[mb][0], bfr[nb][0], acc[mb][nb], 0, 0, 0);
        acc[mb][nb] = __builtin_amdgcn_mfma_f32_16x16x32_bf16(
            af[mb][1], bfr[nb][1], acc[mb][nb], 0, 0, 0);
      }
    __syncthreads();
  }

  const int cbase = n0 + w * 32;
  float bv[2];
#pragma unroll
  for (int nb = 0; nb < 2; ++nb) bv[nb] = bias[cbase + nb * 16 + l15];
#pragma unroll
  for (int mb = 0; mb < 4; ++mb)
#pragma unroll
    for (int nb = 0; nb < 2; ++nb)
#pragma unroll
      for (int r = 0; r < 4; ++r)
        out[(size_t)(m0 + mb * 16 + quad * 4 + r) * 512 + cbase + nb * 16 +
            l15] = acc[mb][nb][r] + bv[nb];
}

// ---------------------------------------------------------------------------
extern "C" void kernel_launch(void* const* d_in, const int* in_sizes, int n_in,
                              void* d_out, int out_size, void* d_ws,
                              size_t ws_size, hipStream_t stream) {
  const float* x     = (const float*)d_in[0];
  const float* W_qkv = (const float*)d_in[1];
  const float* b_qkv = (const float*)d_in[2];
  const float* W_out = (const float*)d_in[3];
  const float* b_out = (const float*)d_in[4];
  float* out = (float*)d_out;

  const size_t NX = (size_t)4 * SEQ_T * D_MODEL;        // 4,194,304
  unsigned short* xb   = (unsigned short*)d_ws;          // [8192][512]
  unsigned short* Wqkt = xb + NX;                        // [1536][512]
  unsigned short* Wot  = Wqkt + (size_t)1536 * 512;      // [512][512]
  unsigned short* Qtb  = Wot + (size_t)512 * 512;        // [bh][d][t]
  unsigned short* Kb   = Qtb + NX;                       // [bh][t][d]
  unsigned short* Vtb  = Kb + NX;                        // [bh][dv][t]
  unsigned short* AOb  = Vtb + NX;                       // [8192][512]

  prep_kernel<<<2304, 256, 0, stream>>>(x, W_qkv, W_out, xb, Wqkt, Wot);
  gemm_qkv_mfma<<<dim3(64, 12), 256, 0, stream>>>(xb, Wqkt, b_qkv, Qtb, Kb,
                                                  Vtb);
  attn_mfma5<<<dim3(1024), 256, 0, stream>>>(Qtb, Kb, Vtb, AOb);
  gemm_out_mfma<<<dim3(128, 4), 256, 0, stream>>>(AOb, Wot, b_out, out);
}